// Round 2
// baseline (947.443 us; speedup 1.0000x reference)
//
#include <hip/hip_runtime.h>
#include <hip/hip_bf16.h>
#include <math.h>

typedef __hip_bfloat16 bf16;
#define NEG_SLOPE 0.2f

// ================= dtype detection =================
// Even-index u16 words of x are real bf16 elements (exp <= ~0x81 for N(0,1))
// if data is bf16; they are f32-mantissa garbage (uniform exponent) if f32.
__global__ void k_detect(const unsigned short* __restrict__ x, int* __restrict__ flag) {
    __shared__ int cnt;
    if (threadIdx.x == 0) cnt = 0;
    __syncthreads();
    int local = 0;
    for (int i = threadIdx.x; i < 2048; i += blockDim.x) {
        unsigned short w = x[2 * i];
        int e = (w >> 7) & 0xFF;
        if (e >= 0x90) local++;
    }
    atomicAdd(&cnt, local);
    __syncthreads();
    if (threadIdx.x == 0) flag[0] = (cnt > 100) ? 1 : 0;  // 1 => inputs are f32
}

#define NSEG 26
struct Seg { const void* src; int n; int off; };
struct Tab { Seg s[NSEG]; };

__global__ void k_convert(Tab tab, float* __restrict__ dst, const int* __restrict__ flag) {
    int f32mode = flag[0];
    for (int s = 0; s < NSEG; s++) {
        Seg sg = tab.s[s];
        for (int i = blockIdx.x * blockDim.x + threadIdx.x; i < sg.n;
             i += gridDim.x * blockDim.x) {
            float v = f32mode ? ((const float*)sg.src)[i]
                              : __bfloat162float(((const bf16*)sg.src)[i]);
            dst[sg.off + i] = v;
        }
    }
}

// ================= CSR build =================
__global__ void k_zero_int(int* p, int n) {
    int i = blockIdx.x * blockDim.x + threadIdx.x;
    if (i < n) p[i] = 0;
}

__global__ void k_count(const int* __restrict__ dstArr, int E, int N, int* __restrict__ deg) {
    int e = blockIdx.x * blockDim.x + threadIdx.x;
    int EA = E + N;
    if (e >= EA) return;
    int d = (e < E) ? dstArr[e] : (e - E);
    atomicAdd(&deg[d], 1);
}

__global__ void k_scan(const int* __restrict__ deg, int* __restrict__ offs, int n) {
    __shared__ int sd[1024];
    __shared__ int srun;
    if (threadIdx.x == 0) srun = 0;
    __syncthreads();
    for (int base = 0; base < n; base += 1024) {
        int i = base + threadIdx.x;
        int v = (i < n) ? deg[i] : 0;
        sd[threadIdx.x] = v;
        __syncthreads();
        for (int off = 1; off < 1024; off <<= 1) {
            int t = (threadIdx.x >= off) ? sd[threadIdx.x - off] : 0;
            __syncthreads();
            sd[threadIdx.x] += t;
            __syncthreads();
        }
        int run = srun;
        if (i < n) offs[i] = run + sd[threadIdx.x] - v;  // exclusive
        __syncthreads();
        if (threadIdx.x == 1023) srun = run + sd[1023];
        __syncthreads();
    }
    if (threadIdx.x == 0) offs[n] = srun;
}

__global__ void k_fill(const int* __restrict__ dstArr, int E, int N,
                       const int* __restrict__ offs, int* __restrict__ cursor,
                       int* __restrict__ csr) {
    int e = blockIdx.x * blockDim.x + threadIdx.x;
    int EA = E + N;
    if (e >= EA) return;
    int d = (e < E) ? dstArr[e] : (e - E);
    int pos = atomicAdd(&cursor[d], 1);
    csr[offs[d] + pos] = e;
}

// ================= agent embedding =================
__global__ void k_embed(const float* __restrict__ xf, const float* __restrict__ W,
                        const float* __restrict__ b, float* __restrict__ out, int N) {
    int gid = blockIdx.x * blockDim.x + threadIdx.x;
    if (gid >= N * 32) return;
    int n = gid >> 5, j = gid & 31;
    const float* xr = xf + (size_t)n * 100;
    float acc = b[j];
    #pragma unroll 10
    for (int k = 0; k < 100; k++) acc += xr[k] * W[k * 32 + j];
    out[gid] = fmaxf(acc, 0.f);
}

// ================= linear =================
template <int FIN, int FOUT>
__global__ void k_linear(const float* __restrict__ x, const float* __restrict__ W,
                         const float* __restrict__ b, float* __restrict__ out, int N) {
    int gid = blockIdx.x * blockDim.x + threadIdx.x;
    if (gid >= N * FOUT) return;
    int n = gid / FOUT, j = gid % FOUT;
    const float* xr = x + (size_t)n * FIN;
    float acc = b[j];
    #pragma unroll 16
    for (int k = 0; k < FIN; k++) acc += xr[k] * W[k * FOUT + j];
    out[gid] = acc;
}

// ================= edge logits (no atomics) =================
template <int H>
__global__ void k_edge_logit(const float* __restrict__ xl, const float* __restrict__ xr,
                             const float* __restrict__ att,
                             const int* __restrict__ srcArr, const int* __restrict__ dstArr,
                             int E, int N, float* __restrict__ logit) {
    const int F = H * 32;
    int ge = blockIdx.x * (blockDim.x >> 5) + (threadIdx.x >> 5);
    int c = threadIdx.x & 31;
    int EA = E + N;
    if (ge >= EA) return;
    int s, d;
    if (ge < E) { s = srcArr[ge]; d = dstArr[ge]; } else { s = d = ge - E; }
    const float* xls = xl + (size_t)s * F;
    const float* xrd = xr + (size_t)d * F;
    #pragma unroll
    for (int h = 0; h < H; h++) {
        float v = xls[h * 32 + c] + xrd[h * 32 + c];
        v = (v > 0.f) ? v : NEG_SLOPE * v;
        float p = v * att[h * 32 + c];
        p += __shfl_xor(p, 16);
        p += __shfl_xor(p, 8);
        p += __shfl_xor(p, 4);
        p += __shfl_xor(p, 2);
        p += __shfl_xor(p, 1);
        if (c == 0) logit[(size_t)ge * H + h] = p;
    }
}

// ================= per-(dst,head) softmax over CSR, in place =================
template <int H>
__global__ void k_alpha(const int* __restrict__ offs, const int* __restrict__ csr,
                        float* __restrict__ logit, int N) {
    int t = blockIdx.x * blockDim.x + threadIdx.x;
    if (t >= N * H) return;
    int d = t / H, h = t % H;
    int i0 = offs[d], i1 = offs[d + 1];
    float mx = -1e30f;
    for (int i = i0; i < i1; i++) mx = fmaxf(mx, logit[(size_t)csr[i] * H + h]);
    float s = 0.f;
    for (int i = i0; i < i1; i++) s += expf(logit[(size_t)csr[i] * H + h] - mx);
    float inv = 1.f / (s + 1e-16f);
    for (int i = i0; i < i1; i++) {
        size_t id = (size_t)csr[i] * H + h;
        logit[id] = expf(logit[id] - mx) * inv;
    }
}

// ================= gather: out[d] = sum alpha * xl[src] + bias, opt relu ======
template <int H, int C>
__global__ void k_gather(const float* __restrict__ xl, const float* __restrict__ alpha,
                         const int* __restrict__ srcArr, int E,
                         const int* __restrict__ offs, const int* __restrict__ csr,
                         const float* __restrict__ bias, float* __restrict__ out, int relu) {
    const int F = H * C;
    int d = blockIdx.x;
    int c = threadIdx.x;
    if (c >= F) return;
    int h = c / C;
    int i0 = offs[d], i1 = offs[d + 1];
    float acc = 0.f;
    for (int i = i0; i < i1; i++) {
        int eid = csr[i];
        int s = (eid < E) ? srcArr[eid] : (eid - E);
        acc += alpha[(size_t)eid * H + h] * xl[(size_t)s * F + c];
    }
    float r = acc + bias[c];
    out[(size_t)d * F + c] = relu ? fmaxf(r, 0.f) : r;
}

// ================= tail =================
__global__ void k_tail(const float* __restrict__ gf, const int* __restrict__ focal,
                       const float* __restrict__ clf, const float* __restrict__ clW,
                       const float* __restrict__ clb, const float* __restrict__ fcW,
                       const float* __restrict__ fcb, void* __restrict__ out,
                       const int* __restrict__ flag) {
    int b = blockIdx.x;
    int t = threadIdx.x;
    __shared__ float comb[64];
    __shared__ float ssum[2];
    if (t < 2) {
        float s = 0.f;
        for (int l = 0; l < 50; l++) s += clf[(size_t)b * 100 + l * 2 + t];
        ssum[t] = s / 50.f;
    }
    if (t < 32) comb[t] = gf[(size_t)focal[b] * 32 + t];
    __syncthreads();
    if (t < 32) comb[32 + t] = ssum[0] * clW[t] + ssum[1] * clW[32 + t] + clb[t];
    __syncthreads();
    if (t < 60) {
        float acc = fcb[t];
        #pragma unroll 16
        for (int k = 0; k < 64; k++) acc += comb[k] * fcW[k * 60 + t];
        if (flag[0]) ((float*)out)[b * 60 + t] = acc;
        else ((bf16*)out)[b * 60 + t] = __float2bfloat16(acc);
    }
}

extern "C" void kernel_launch(void* const* d_in, const int* in_sizes, int n_in,
                              void* d_out, int out_size, void* d_ws, size_t ws_size,
                              hipStream_t stream) {
    const int* edge  = (const int*)d_in[1];
    const int* focal = (const int*)d_in[5];

    const int N = in_sizes[0] / 100;   // 20000
    const int E = in_sizes[1] / 2;     // 320000
    const int B = in_sizes[5];         // 64
    const int EA = E + N;
    const int* srcArr = edge;
    const int* dstArr = edge + E;

    // ---- conversion table: all float inputs -> fp32 in ws ----
    // weight inputs first, then x, then centerlines
    const int idxs[NSEG] = {7,8,9,10,11,12,13,14,15,16,17,18,19,20,
                            35,36,37,38,39,40,41,42,43,44, 0, 6};
    float* base = (float*)d_ws;
    int* flag = (int*)base;            // base[0..15] reserved
    float* wf = base + 16;
    Tab tab;
    int off[NSEG];
    int o = 0;
    for (int i = 0; i < NSEG; i++) {
        tab.s[i].src = d_in[idxs[i]];
        tab.s[i].n   = in_sizes[idxs[i]];
        tab.s[i].off = o;
        off[i] = o;
        o += in_sizes[idxs[i]];
    }
    const float* aeW  = wf + off[0],  *aeb  = wf + off[1];
    const float* a1Wl = wf + off[2],  *a1bl = wf + off[3];
    const float* a1Wr = wf + off[4],  *a1br = wf + off[5];
    const float* a1att= wf + off[6],  *a1b  = wf + off[7];
    const float* a2Wl = wf + off[8],  *a2bl = wf + off[9];
    const float* a2Wr = wf + off[10], *a2br = wf + off[11];
    const float* a2att= wf + off[12], *a2b  = wf + off[13];
    const float* clW  = wf + off[14], *clb  = wf + off[15];
    const float* gWl  = wf + off[16], *gbl  = wf + off[17];
    const float* gWr  = wf + off[18], *gbr  = wf + off[19];
    const float* gatt = wf + off[20], *gb   = wf + off[21];
    const float* fcW  = wf + off[22], *fcb  = wf + off[23];
    const float* xf   = wf + off[24];
    const float* clf  = wf + off[25];

    // ---- remaining workspace ----
    float* p = wf + o;
    size_t N128 = (size_t)N * 128;
    float* ax    = p;               p += (size_t)N * 32;
    float* fA    = p;               p += N128;   // xl
    float* fB    = p;               p += N128;   // xr / global xl,xr,gf
    float* fC    = p;               p += N128;   // h / agent_features
    float* logit = p;               p += (size_t)EA * 4;
    int* deg    = (int*)p;
    int* cursor = deg + N;
    int* offs   = cursor + N;       // N+1
    int* csr    = offs + N + 1;     // EA

    const int T = 256;
    // ---- dtype detect + convert ----
    k_detect<<<1, 256, 0, stream>>>((const unsigned short*)d_in[0], flag);
    k_convert<<<1024, 256, 0, stream>>>(tab, wf, flag);

    // ---- CSR build (shared by all 3 GAT layers) ----
    k_zero_int<<<(2 * N + T - 1) / T, T, 0, stream>>>(deg, 2 * N);
    k_count<<<(EA + T - 1) / T, T, 0, stream>>>(dstArr, E, N, deg);
    k_scan<<<1, 1024, 0, stream>>>(deg, offs, N);
    k_fill<<<(EA + T - 1) / T, T, 0, stream>>>(dstArr, E, N, offs, cursor, csr);

    // ---- agent embedding ----
    k_embed<<<(N * 32 + T - 1) / T, T, 0, stream>>>(xf, aeW, aeb, ax, N);

    // ---- conv1 ----
    k_linear<32, 128><<<(N * 128 + T - 1) / T, T, 0, stream>>>(ax, a1Wl, a1bl, fA, N);
    k_linear<32, 128><<<(N * 128 + T - 1) / T, T, 0, stream>>>(ax, a1Wr, a1br, fB, N);
    k_edge_logit<4><<<(EA + 7) / 8, 256, 0, stream>>>(fA, fB, a1att, srcArr, dstArr, E, N, logit);
    k_alpha<4><<<(N * 4 + T - 1) / T, T, 0, stream>>>(offs, csr, logit, N);
    k_gather<4, 32><<<N, 128, 0, stream>>>(fA, logit, srcArr, E, offs, csr, a1b, fC, 1);

    // ---- conv2 (out overwrites input fC only after linears consumed it) ----
    k_linear<128, 128><<<(N * 128 + T - 1) / T, T, 0, stream>>>(fC, a2Wl, a2bl, fA, N);
    k_linear<128, 128><<<(N * 128 + T - 1) / T, T, 0, stream>>>(fC, a2Wr, a2br, fB, N);
    k_edge_logit<4><<<(EA + 7) / 8, 256, 0, stream>>>(fA, fB, a2att, srcArr, dstArr, E, N, logit);
    k_alpha<4><<<(N * 4 + T - 1) / T, T, 0, stream>>>(offs, csr, logit, N);
    k_gather<4, 32><<<N, 128, 0, stream>>>(fA, logit, srcArr, E, offs, csr, a2b, fC, 1);

    // ---- global graph (heads=1), packed into fB ----
    float* xlg = fB;
    float* xrg = fB + (size_t)N * 32;
    float* gf  = fB + (size_t)N * 64;
    k_linear<128, 32><<<(N * 32 + T - 1) / T, T, 0, stream>>>(fC, gWl, gbl, xlg, N);
    k_linear<128, 32><<<(N * 32 + T - 1) / T, T, 0, stream>>>(fC, gWr, gbr, xrg, N);
    k_edge_logit<1><<<(EA + 7) / 8, 256, 0, stream>>>(xlg, xrg, gatt, srcArr, dstArr, E, N, logit);
    k_alpha<1><<<(N + T - 1) / T, T, 0, stream>>>(offs, csr, logit, N);
    k_gather<1, 32><<<N, 64, 0, stream>>>(xlg, logit, srcArr, E, offs, csr, gb, gf, 1);

    // ---- tail ----
    k_tail<<<B, 64, 0, stream>>>(gf, focal, clf, clW, clb, fcW, fcb, d_out, flag);
}

// Round 3
// 588.359 us; speedup vs baseline: 1.6103x; 1.6103x over previous
//
#include <hip/hip_runtime.h>
#include <hip/hip_bf16.h>
#include <math.h>

typedef __hip_bfloat16 bf16;
#define NEG_SLOPE 0.2f

// ================= dtype detection =================
__global__ void k_detect(const unsigned short* __restrict__ x, int* __restrict__ flag) {
    __shared__ int cnt;
    if (threadIdx.x == 0) cnt = 0;
    __syncthreads();
    int local = 0;
    for (int i = threadIdx.x; i < 2048; i += blockDim.x) {
        unsigned short w = x[2 * i];
        int e = (w >> 7) & 0xFF;
        if (e >= 0x90) local++;
    }
    atomicAdd(&cnt, local);
    __syncthreads();
    if (threadIdx.x == 0) flag[0] = (cnt > 100) ? 1 : 0;  // 1 => inputs are f32
}

#define NSEG 26
struct Seg { const void* src; int n; int off; };
struct Tab { Seg s[NSEG]; };

__global__ void k_convert(Tab tab, float* __restrict__ dst, const int* __restrict__ flag) {
    int f32mode = flag[0];
    for (int s = 0; s < NSEG; s++) {
        Seg sg = tab.s[s];
        for (int i = blockIdx.x * blockDim.x + threadIdx.x; i < sg.n;
             i += gridDim.x * blockDim.x) {
            float v = f32mode ? ((const float*)sg.src)[i]
                              : __bfloat162float(((const bf16*)sg.src)[i]);
            dst[sg.off + i] = v;
        }
    }
}

// ================= CSR build =================
__global__ void k_zero_int(int* p, int n) {
    int i = blockIdx.x * blockDim.x + threadIdx.x;
    if (i < n) p[i] = 0;
}

__global__ void k_count(const int* __restrict__ dstArr, int E, int N, int* __restrict__ deg) {
    int e = blockIdx.x * blockDim.x + threadIdx.x;
    int EA = E + N;
    if (e >= EA) return;
    int d = (e < E) ? dstArr[e] : (e - E);
    atomicAdd(&deg[d], 1);
}

__global__ void k_scan(const int* __restrict__ deg, int* __restrict__ offs, int n) {
    __shared__ int sd[1024];
    __shared__ int srun;
    if (threadIdx.x == 0) srun = 0;
    __syncthreads();
    for (int base = 0; base < n; base += 1024) {
        int i = base + threadIdx.x;
        int v = (i < n) ? deg[i] : 0;
        sd[threadIdx.x] = v;
        __syncthreads();
        for (int off = 1; off < 1024; off <<= 1) {
            int t = (threadIdx.x >= off) ? sd[threadIdx.x - off] : 0;
            __syncthreads();
            sd[threadIdx.x] += t;
            __syncthreads();
        }
        int run = srun;
        if (i < n) offs[i] = run + sd[threadIdx.x] - v;  // exclusive
        __syncthreads();
        if (threadIdx.x == 1023) srun = run + sd[1023];
        __syncthreads();
    }
    if (threadIdx.x == 0) offs[n] = srun;
}

__global__ void k_fill(const int* __restrict__ dstArr, int E, int N,
                       const int* __restrict__ offs, int* __restrict__ cursor,
                       int* __restrict__ csr) {
    int e = blockIdx.x * blockDim.x + threadIdx.x;
    int EA = E + N;
    if (e >= EA) return;
    int d = (e < E) ? dstArr[e] : (e - E);
    int pos = atomicAdd(&cursor[d], 1);
    csr[offs[d] + pos] = e;
}

// ================= fused dual linear: outl = x@Wl+bl, outr = x@Wr+br =========
// x-tile transposed in LDS; thread = (j, half, node-group); 4 nodes per float4.
template <int FIN, int FOUT, int HALVES, int NT, int RELU>
__launch_bounds__(256)
__global__ void k_lin(const float* __restrict__ x,
                      const float* __restrict__ Wl, const float* __restrict__ bl,
                      const float* __restrict__ Wr, const float* __restrict__ br,
                      float* __restrict__ outl, float* __restrict__ outr) {
    constexpr int NTP = NT + 4;                      // pad: breaks bank aliasing, keeps 16B align
    constexpr int NGT = 256 / (FOUT * HALVES);       // thread node-groups
    constexpr int GPT = (NT / 4) / NGT;              // groups per thread
    __shared__ float xs[FIN * NTP];
    int t = threadIdx.x;
    int nb = blockIdx.x * NT;

    // load + transpose x tile
    const float4* x4 = (const float4*)x;
    for (int idx = t; idx < NT * (FIN / 4); idx += 256) {
        int node = idx / (FIN / 4);
        int k4 = idx % (FIN / 4);
        float4 v = x4[(size_t)(nb + node) * (FIN / 4) + k4];
        xs[(k4 * 4 + 0) * NTP + node] = v.x;
        xs[(k4 * 4 + 1) * NTP + node] = v.y;
        xs[(k4 * 4 + 2) * NTP + node] = v.z;
        xs[(k4 * 4 + 3) * NTP + node] = v.w;
    }
    __syncthreads();

    int j = t % FOUT;
    int rest = t / FOUT;
    int half = rest % HALVES;
    int g0 = rest / HALVES;
    const float* Wp = (HALVES == 2 && half) ? Wr : Wl;
    const float* bp = (HALVES == 2 && half) ? br : bl;
    float bj = bp[j];

    float acc[GPT][4];
    #pragma unroll
    for (int g = 0; g < GPT; g++) { acc[g][0]=0.f; acc[g][1]=0.f; acc[g][2]=0.f; acc[g][3]=0.f; }

    for (int k = 0; k < FIN; k++) {
        float w = Wp[(size_t)k * FOUT + j];
        #pragma unroll
        for (int g = 0; g < GPT; g++) {
            int gg = g0 + g * NGT;
            const float4 xv = *(const float4*)&xs[k * NTP + gg * 4];
            acc[g][0] += w * xv.x;
            acc[g][1] += w * xv.y;
            acc[g][2] += w * xv.z;
            acc[g][3] += w * xv.w;
        }
    }

    float* op = (HALVES == 2 && half) ? outr : outl;
    #pragma unroll
    for (int g = 0; g < GPT; g++) {
        int gg = g0 + g * NGT;
        #pragma unroll
        for (int c = 0; c < 4; c++) {
            float v = acc[g][c] + bj;
            if (RELU) v = fmaxf(v, 0.f);
            op[(size_t)(nb + gg * 4 + c) * FOUT + j] = v;
        }
    }
}

// ================= fused GAT layer, block per dst node (H heads of C=32) =====
#define CAP 256
template <int H>
__global__ void k_gat(const float* __restrict__ xl, const float* __restrict__ xr,
                      const float* __restrict__ att, const int* __restrict__ srcArr,
                      int E, const int* __restrict__ offs, const int* __restrict__ csr,
                      const float* __restrict__ bias, float* __restrict__ out) {
    const int F = H * 32;  // blockDim.x == F
    __shared__ float slog[CAP * H];
    int d = blockIdx.x;
    int t = threadIdx.x;
    int h = t >> 5;
    int c32 = t & 31;
    int i0 = offs[d], i1 = offs[d + 1];
    int deg = i1 - i0;
    if (deg > CAP) { deg = CAP; i1 = i0 + CAP; }
    float xrd = xr[(size_t)d * F + t];
    float av = att[t];

    // pass 1: logits
    for (int i = i0; i < i1; i++) {
        int e = csr[i];
        int s = (e < E) ? srcArr[e] : (e - E);
        float v = xl[(size_t)s * F + t] + xrd;
        v = (v > 0.f) ? v : NEG_SLOPE * v;
        float p = v * av;
        p += __shfl_xor(p, 16);
        p += __shfl_xor(p, 8);
        p += __shfl_xor(p, 4);
        p += __shfl_xor(p, 2);
        p += __shfl_xor(p, 1);
        if (c32 == 0) slog[(i - i0) * H + h] = p;
    }
    __syncthreads();

    // softmax per head: 32 lanes strided over deg entries
    float mx = -1e30f;
    for (int jj = c32; jj < deg; jj += 32) mx = fmaxf(mx, slog[jj * H + h]);
    mx = fmaxf(mx, __shfl_xor(mx, 16));
    mx = fmaxf(mx, __shfl_xor(mx, 8));
    mx = fmaxf(mx, __shfl_xor(mx, 4));
    mx = fmaxf(mx, __shfl_xor(mx, 2));
    mx = fmaxf(mx, __shfl_xor(mx, 1));
    float sm = 0.f;
    for (int jj = c32; jj < deg; jj += 32) {
        float ev = expf(slog[jj * H + h] - mx);
        slog[jj * H + h] = ev;
        sm += ev;
    }
    sm += __shfl_xor(sm, 16);
    sm += __shfl_xor(sm, 8);
    sm += __shfl_xor(sm, 4);
    sm += __shfl_xor(sm, 2);
    sm += __shfl_xor(sm, 1);
    float inv = 1.f / (sm + 1e-16f);
    __syncthreads();

    // pass 2: weighted gather
    float acc = 0.f;
    for (int i = i0; i < i1; i++) {
        int e = csr[i];
        int s = (e < E) ? srcArr[e] : (e - E);
        acc += slog[(i - i0) * H + h] * xl[(size_t)s * F + t];
    }
    out[(size_t)d * F + t] = fmaxf(acc * inv + bias[t], 0.f);
}

// ================= fused GAT global layer (H=1, C=32), 1 wave per dst ========
__global__ void k_gat_g(const float* __restrict__ xl, const float* __restrict__ xr,
                        const float* __restrict__ att, const int* __restrict__ srcArr,
                        int E, const int* __restrict__ offs, const int* __restrict__ csr,
                        const float* __restrict__ bias, float* __restrict__ out) {
    __shared__ float slog[CAP];
    int d = blockIdx.x;
    int t = threadIdx.x;   // 64
    int c = t & 31, eh = t >> 5;
    int i0 = offs[d], i1 = offs[d + 1];
    int deg = i1 - i0;
    if (deg > CAP) { deg = CAP; i1 = i0 + CAP; }
    float xrd = xr[(size_t)d * 32 + c];
    float av = att[c];

    for (int i = i0 + eh; i < i1; i += 2) {
        int e = csr[i];
        int s = (e < E) ? srcArr[e] : (e - E);
        float v = xl[(size_t)s * 32 + c] + xrd;
        v = (v > 0.f) ? v : NEG_SLOPE * v;
        float p = v * av;
        p += __shfl_xor(p, 16);
        p += __shfl_xor(p, 8);
        p += __shfl_xor(p, 4);
        p += __shfl_xor(p, 2);
        p += __shfl_xor(p, 1);
        if (c == 0) slog[i - i0] = p;
    }
    __syncthreads();

    float mx = -1e30f;
    for (int jj = t; jj < deg; jj += 64) mx = fmaxf(mx, slog[jj]);
    mx = fmaxf(mx, __shfl_xor(mx, 32));
    mx = fmaxf(mx, __shfl_xor(mx, 16));
    mx = fmaxf(mx, __shfl_xor(mx, 8));
    mx = fmaxf(mx, __shfl_xor(mx, 4));
    mx = fmaxf(mx, __shfl_xor(mx, 2));
    mx = fmaxf(mx, __shfl_xor(mx, 1));
    float sm = 0.f;
    for (int jj = t; jj < deg; jj += 64) {
        float ev = expf(slog[jj] - mx);
        slog[jj] = ev;
        sm += ev;
    }
    sm += __shfl_xor(sm, 32);
    sm += __shfl_xor(sm, 16);
    sm += __shfl_xor(sm, 8);
    sm += __shfl_xor(sm, 4);
    sm += __shfl_xor(sm, 2);
    sm += __shfl_xor(sm, 1);
    float inv = 1.f / (sm + 1e-16f);
    __syncthreads();

    float acc = 0.f;
    for (int i = i0 + eh; i < i1; i += 2) {
        int e = csr[i];
        int s = (e < E) ? srcArr[e] : (e - E);
        acc += slog[i - i0] * xl[(size_t)s * 32 + c];
    }
    acc += __shfl_xor(acc, 32);
    if (eh == 0) out[(size_t)d * 32 + c] = fmaxf(acc * inv + bias[c], 0.f);
}

// ================= tail =================
__global__ void k_tail(const float* __restrict__ gf, const int* __restrict__ focal,
                       const float* __restrict__ clf, const float* __restrict__ clW,
                       const float* __restrict__ clb, const float* __restrict__ fcW,
                       const float* __restrict__ fcb, void* __restrict__ out,
                       const int* __restrict__ flag) {
    int b = blockIdx.x;
    int t = threadIdx.x;
    __shared__ float comb[64];
    __shared__ float ssum[2];
    if (t < 2) {
        float s = 0.f;
        for (int l = 0; l < 50; l++) s += clf[(size_t)b * 100 + l * 2 + t];
        ssum[t] = s / 50.f;
    }
    if (t < 32) comb[t] = gf[(size_t)focal[b] * 32 + t];
    __syncthreads();
    if (t < 32) comb[32 + t] = ssum[0] * clW[t] + ssum[1] * clW[32 + t] + clb[t];
    __syncthreads();
    if (t < 60) {
        float acc = fcb[t];
        #pragma unroll 16
        for (int k = 0; k < 64; k++) acc += comb[k] * fcW[k * 60 + t];
        if (flag[0]) ((float*)out)[b * 60 + t] = acc;
        else ((bf16*)out)[b * 60 + t] = __float2bfloat16(acc);
    }
}

extern "C" void kernel_launch(void* const* d_in, const int* in_sizes, int n_in,
                              void* d_out, int out_size, void* d_ws, size_t ws_size,
                              hipStream_t stream) {
    const int* edge  = (const int*)d_in[1];
    const int* focal = (const int*)d_in[5];

    const int N = in_sizes[0] / 100;   // 20000
    const int E = in_sizes[1] / 2;     // 320000
    const int B = in_sizes[5];         // 64
    const int EA = E + N;
    const int* srcArr = edge;
    const int* dstArr = edge + E;

    // ---- conversion table: all float inputs -> fp32 in ws ----
    const int idxs[NSEG] = {7,8,9,10,11,12,13,14,15,16,17,18,19,20,
                            35,36,37,38,39,40,41,42,43,44, 0, 6};
    float* base = (float*)d_ws;
    int* flag = (int*)base;            // base[0..15] reserved
    float* wf = base + 16;
    Tab tab;
    int off[NSEG];
    int o = 0;
    for (int i = 0; i < NSEG; i++) {
        tab.s[i].src = d_in[idxs[i]];
        tab.s[i].n   = in_sizes[idxs[i]];
        tab.s[i].off = o;
        off[i] = o;
        o += in_sizes[idxs[i]];
    }
    const float* aeW  = wf + off[0],  *aeb  = wf + off[1];
    const float* a1Wl = wf + off[2],  *a1bl = wf + off[3];
    const float* a1Wr = wf + off[4],  *a1br = wf + off[5];
    const float* a1att= wf + off[6],  *a1b  = wf + off[7];
    const float* a2Wl = wf + off[8],  *a2bl = wf + off[9];
    const float* a2Wr = wf + off[10], *a2br = wf + off[11];
    const float* a2att= wf + off[12], *a2b  = wf + off[13];
    const float* clW  = wf + off[14], *clb  = wf + off[15];
    const float* gWl  = wf + off[16], *gbl  = wf + off[17];
    const float* gWr  = wf + off[18], *gbr  = wf + off[19];
    const float* gatt = wf + off[20], *gb   = wf + off[21];
    const float* fcW  = wf + off[22], *fcb  = wf + off[23];
    const float* xf   = wf + off[24];
    const float* clf  = wf + off[25];

    // ---- remaining workspace ----
    float* p = wf + o;
    size_t N128 = (size_t)N * 128;
    float* ax = p;                  p += (size_t)N * 32;   // embed out
    float* fA = p;                  p += N128;             // xl  (later: xlg/xrg/gf)
    float* fB = p;                  p += N128;             // xr
    float* fC = p;                  p += N128;             // h / agent_features
    int* deg    = (int*)p;
    int* cursor = deg + N;
    int* offs   = cursor + N;       // N+1
    int* csr    = offs + N + 1;     // EA

    const int T = 256;
    // ---- dtype detect + convert ----
    k_detect<<<1, 256, 0, stream>>>((const unsigned short*)d_in[0], flag);
    k_convert<<<1024, 256, 0, stream>>>(tab, wf, flag);

    // ---- CSR build (shared by all 3 GAT layers) ----
    k_zero_int<<<(2 * N + T - 1) / T, T, 0, stream>>>(deg, 2 * N);
    k_count<<<(EA + T - 1) / T, T, 0, stream>>>(dstArr, E, N, deg);
    k_scan<<<1, 1024, 0, stream>>>(deg, offs, N);
    k_fill<<<(EA + T - 1) / T, T, 0, stream>>>(dstArr, E, N, offs, cursor, csr);

    // ---- agent embedding: relu(x@aeW + aeb) ----
    k_lin<100, 32, 1, 32, 1><<<N / 32, 256, 0, stream>>>(xf, aeW, aeb, aeW, aeb, ax, ax);

    // ---- conv1 ----
    k_lin<32, 128, 2, 32, 0><<<N / 32, 256, 0, stream>>>(ax, a1Wl, a1bl, a1Wr, a1br, fA, fB);
    k_gat<4><<<N, 128, 0, stream>>>(fA, fB, a1att, srcArr, E, offs, csr, a1b, fC);

    // ---- conv2 ----
    k_lin<128, 128, 2, 32, 0><<<N / 32, 256, 0, stream>>>(fC, a2Wl, a2bl, a2Wr, a2br, fA, fB);
    k_gat<4><<<N, 128, 0, stream>>>(fA, fB, a2att, srcArr, E, offs, csr, a2b, fC);

    // ---- global graph (heads=1) ----
    float* xlg = fA;
    float* xrg = fA + (size_t)N * 32;
    float* gf  = fA + (size_t)N * 64;
    k_lin<128, 32, 2, 32, 0><<<N / 32, 256, 0, stream>>>(fC, gWl, gbl, gWr, gbr, xlg, xrg);
    k_gat_g<<<N, 64, 0, stream>>>(xlg, xrg, gatt, srcArr, E, offs, csr, gb, gf);

    // ---- tail ----
    k_tail<<<B, 64, 0, stream>>>(gf, focal, clf, clW, clb, fcW, fcb, d_out, flag);
}

// Round 4
// 386.645 us; speedup vs baseline: 2.4504x; 1.5217x over previous
//
#include <hip/hip_runtime.h>
#include <hip/hip_bf16.h>
#include <math.h>

typedef __hip_bfloat16 bf16;
#define NEG_SLOPE 0.2f

// ================= dtype detection =================
__global__ void k_detect(const unsigned short* __restrict__ x, int* __restrict__ flag) {
    __shared__ int cnt;
    if (threadIdx.x == 0) cnt = 0;
    __syncthreads();
    int local = 0;
    for (int i = threadIdx.x; i < 2048; i += blockDim.x) {
        unsigned short w = x[2 * i];
        int e = (w >> 7) & 0xFF;
        if (e >= 0x90) local++;
    }
    atomicAdd(&cnt, local);
    __syncthreads();
    if (threadIdx.x == 0) flag[0] = (cnt > 100) ? 1 : 0;  // 1 => inputs are f32
}

#define NSEG 26
struct Seg { const void* src; int n; int off; };
struct Tab { Seg s[NSEG]; };

__global__ void k_convert(Tab tab, float* __restrict__ dst, const int* __restrict__ flag) {
    int f32mode = flag[0];
    for (int s = 0; s < NSEG; s++) {
        Seg sg = tab.s[s];
        for (int i = blockIdx.x * blockDim.x + threadIdx.x; i < sg.n;
             i += gridDim.x * blockDim.x) {
            float v = f32mode ? ((const float*)sg.src)[i]
                              : __bfloat162float(((const bf16*)sg.src)[i]);
            dst[sg.off + i] = v;
        }
    }
}

// ================= CSR build =================
__global__ void k_zero_int(int* p, int n) {
    int i = blockIdx.x * blockDim.x + threadIdx.x;
    if (i < n) p[i] = 0;
}

__global__ void k_count(const int* __restrict__ dstArr, int E, int N, int* __restrict__ deg) {
    int e = blockIdx.x * blockDim.x + threadIdx.x;
    int EA = E + N;
    if (e >= EA) return;
    int d = (e < E) ? dstArr[e] : (e - E);
    atomicAdd(&deg[d], 1);
}

// single-block scan, wave-shuffle based (4 barriers per 1024-chunk)
__global__ void k_scan(const int* __restrict__ deg, int* __restrict__ offs, int n) {
    __shared__ int wsum[16];
    __shared__ int woff[16];
    __shared__ int stot;
    __shared__ int srun_s;
    int tid = threadIdx.x;
    int lane = tid & 63, wid = tid >> 6;
    if (tid == 0) srun_s = 0;
    __syncthreads();
    for (int base = 0; base < n; base += 1024) {
        int i = base + tid;
        int v = (i < n) ? deg[i] : 0;
        int x = v;
        #pragma unroll
        for (int o = 1; o < 64; o <<= 1) {
            int y = __shfl_up(x, o);
            if (lane >= o) x += y;
        }
        if (lane == 63) wsum[wid] = x;
        int run = srun_s;
        __syncthreads();
        if (wid == 0) {
            int w = (lane < 16) ? wsum[lane] : 0;
            int ws = w;
            #pragma unroll
            for (int o = 1; o < 16; o <<= 1) {
                int y = __shfl_up(ws, o);
                if (lane >= o) ws += y;
            }
            if (lane < 16) woff[lane] = ws - w;
            if (lane == 15) stot = ws;
        }
        __syncthreads();
        if (i < n) offs[i] = run + woff[wid] + x - v;  // exclusive
        if (tid == 0) srun_s = run + stot;
        __syncthreads();
    }
    if (threadIdx.x == 0) offs[n] = srun_s;
}

// csr stores SRC NODE IDS directly (self-loop => d itself)
__global__ void k_fill(const int* __restrict__ srcArr, const int* __restrict__ dstArr,
                       int E, int N, const int* __restrict__ offs,
                       int* __restrict__ cursor, int* __restrict__ csr) {
    int e = blockIdx.x * blockDim.x + threadIdx.x;
    int EA = E + N;
    if (e >= EA) return;
    int d, s;
    if (e < E) { d = dstArr[e]; s = srcArr[e]; } else { d = s = e - E; }
    int pos = atomicAdd(&cursor[d], 1);
    csr[offs[d] + pos] = s;
}

// ================= fused dual linear: outl = x@Wl+bl, outr = x@Wr+br =========
template <int FIN, int FOUT, int HALVES, int NT, int RELU>
__launch_bounds__(256)
__global__ void k_lin(const float* __restrict__ x,
                      const float* __restrict__ Wl, const float* __restrict__ bl,
                      const float* __restrict__ Wr, const float* __restrict__ br,
                      float* __restrict__ outl, float* __restrict__ outr) {
    constexpr int NTP = NT + 4;
    constexpr int NGT = 256 / (FOUT * HALVES);
    constexpr int GPT = (NT / 4) / NGT;
    __shared__ float xs[FIN * NTP];
    int t = threadIdx.x;
    int nb = blockIdx.x * NT;

    const float4* x4 = (const float4*)x;
    for (int idx = t; idx < NT * (FIN / 4); idx += 256) {
        int node = idx / (FIN / 4);
        int k4 = idx % (FIN / 4);
        float4 v = x4[(size_t)(nb + node) * (FIN / 4) + k4];
        xs[(k4 * 4 + 0) * NTP + node] = v.x;
        xs[(k4 * 4 + 1) * NTP + node] = v.y;
        xs[(k4 * 4 + 2) * NTP + node] = v.z;
        xs[(k4 * 4 + 3) * NTP + node] = v.w;
    }
    __syncthreads();

    int j = t % FOUT;
    int rest = t / FOUT;
    int half = rest % HALVES;
    int g0 = rest / HALVES;
    const float* Wp = (HALVES == 2 && half) ? Wr : Wl;
    const float* bp = (HALVES == 2 && half) ? br : bl;
    float bj = bp[j];

    float acc[GPT][4];
    #pragma unroll
    for (int g = 0; g < GPT; g++) { acc[g][0]=0.f; acc[g][1]=0.f; acc[g][2]=0.f; acc[g][3]=0.f; }

    for (int k = 0; k < FIN; k++) {
        float w = Wp[(size_t)k * FOUT + j];
        #pragma unroll
        for (int g = 0; g < GPT; g++) {
            int gg = g0 + g * NGT;
            const float4 xv = *(const float4*)&xs[k * NTP + gg * 4];
            acc[g][0] += w * xv.x;
            acc[g][1] += w * xv.y;
            acc[g][2] += w * xv.z;
            acc[g][3] += w * xv.w;
        }
    }

    float* op = (HALVES == 2 && half) ? outr : outl;
    #pragma unroll
    for (int g = 0; g < GPT; g++) {
        int gg = g0 + g * NGT;
        #pragma unroll
        for (int c = 0; c < 4; c++) {
            float v = acc[g][c] + bj;
            if (RELU) v = fmaxf(v, 0.f);
            op[(size_t)(nb + gg * 4 + c) * FOUT + j] = v;
        }
    }
}

// ===== fused GAT layer, single-pass online softmax, block per dst ===========
template <int H>
__launch_bounds__(H * 32)
__global__ void k_gat(const float* __restrict__ xl, const float* __restrict__ xr,
                      const float* __restrict__ att,
                      const int* __restrict__ offs, const int* __restrict__ csr,
                      const float* __restrict__ bias, float* __restrict__ out) {
    const int F = H * 32;   // blockDim.x == F
    int d = blockIdx.x;
    int t = threadIdx.x;
    int i0 = offs[d], i1 = offs[d + 1];
    float xrd = xr[(size_t)d * F + t];
    float av = att[t];
    float mx = -1e30f, sm = 0.f, acc = 0.f;

    auto proc = [&](float v) {
        float u = v + xrd;
        u = (u > 0.f) ? u : NEG_SLOPE * u;
        float p = u * av;
        p += __shfl_xor(p, 16);
        p += __shfl_xor(p, 8);
        p += __shfl_xor(p, 4);
        p += __shfl_xor(p, 2);
        p += __shfl_xor(p, 1);
        float nm = fmaxf(mx, p);
        float scale = __expf(mx - nm);
        float w = __expf(p - nm);
        sm = sm * scale + w;
        acc = acc * scale + w * v;
        mx = nm;
    };

    int i = i0;
    for (; i + 4 <= i1; i += 4) {
        int s0 = csr[i], s1 = csr[i + 1], s2 = csr[i + 2], s3 = csr[i + 3];
        float v0 = xl[(size_t)s0 * F + t];
        float v1 = xl[(size_t)s1 * F + t];
        float v2 = xl[(size_t)s2 * F + t];
        float v3 = xl[(size_t)s3 * F + t];
        proc(v0); proc(v1); proc(v2); proc(v3);
    }
    for (; i < i1; i++) {
        float v = xl[(size_t)csr[i] * F + t];
        proc(v);
    }
    out[(size_t)d * F + t] = fmaxf(acc / (sm + 1e-16f) + bias[t], 0.f);
}

// ===== fused GAT global layer (H=1, C=32), 1 wave per dst, 2 edge-halves ====
__launch_bounds__(64)
__global__ void k_gat_g(const float* __restrict__ xl, const float* __restrict__ xr,
                        const float* __restrict__ att,
                        const int* __restrict__ offs, const int* __restrict__ csr,
                        const float* __restrict__ bias, float* __restrict__ out) {
    int d = blockIdx.x;
    int t = threadIdx.x;           // 64
    int c = t & 31, eh = t >> 5;   // half 0/1
    int i0 = offs[d], i1 = offs[d + 1];
    float xrd = xr[(size_t)d * 32 + c];
    float av = att[c];
    float mx = -1e30f, sm = 0.f, acc = 0.f;

    auto proc = [&](float v) {
        float u = v + xrd;
        u = (u > 0.f) ? u : NEG_SLOPE * u;
        float p = u * av;
        p += __shfl_xor(p, 16);
        p += __shfl_xor(p, 8);
        p += __shfl_xor(p, 4);
        p += __shfl_xor(p, 2);
        p += __shfl_xor(p, 1);
        float nm = fmaxf(mx, p);
        float scale = __expf(mx - nm);
        float w = __expf(p - nm);
        sm = sm * scale + w;
        acc = acc * scale + w * v;
        mx = nm;
    };

    int i = i0 + eh;
    for (; i + 2 < i1; i += 4) {
        int s0 = csr[i], s1 = csr[i + 2];
        float v0 = xl[(size_t)s0 * 32 + c];
        float v1 = xl[(size_t)s1 * 32 + c];
        proc(v0); proc(v1);
    }
    for (; i < i1; i += 2) {
        float v = xl[(size_t)csr[i] * 32 + c];
        proc(v);
    }
    // merge the two halves
    float mxo = __shfl_xor(mx, 32);
    float smo = __shfl_xor(sm, 32);
    float acco = __shfl_xor(acc, 32);
    float M = fmaxf(mx, mxo);
    float e0 = __expf(mx - M), e1 = __expf(mxo - M);
    float S = sm * e0 + smo * e1;
    float A = acc * e0 + acco * e1;
    if (eh == 0) out[(size_t)d * 32 + c] = fmaxf(A / (S + 1e-16f) + bias[c], 0.f);
}

// ================= tail =================
__global__ void k_tail(const float* __restrict__ gf, const int* __restrict__ focal,
                       const float* __restrict__ clf, const float* __restrict__ clW,
                       const float* __restrict__ clb, const float* __restrict__ fcW,
                       const float* __restrict__ fcb, void* __restrict__ out,
                       const int* __restrict__ flag) {
    int b = blockIdx.x;
    int t = threadIdx.x;
    __shared__ float comb[64];
    __shared__ float ssum[2];
    if (t < 2) {
        float s = 0.f;
        for (int l = 0; l < 50; l++) s += clf[(size_t)b * 100 + l * 2 + t];
        ssum[t] = s / 50.f;
    }
    if (t < 32) comb[t] = gf[(size_t)focal[b] * 32 + t];
    __syncthreads();
    if (t < 32) comb[32 + t] = ssum[0] * clW[t] + ssum[1] * clW[32 + t] + clb[t];
    __syncthreads();
    if (t < 60) {
        float acc = fcb[t];
        #pragma unroll 16
        for (int k = 0; k < 64; k++) acc += comb[k] * fcW[k * 60 + t];
        if (flag[0]) ((float*)out)[b * 60 + t] = acc;
        else ((bf16*)out)[b * 60 + t] = __float2bfloat16(acc);
    }
}

extern "C" void kernel_launch(void* const* d_in, const int* in_sizes, int n_in,
                              void* d_out, int out_size, void* d_ws, size_t ws_size,
                              hipStream_t stream) {
    const int* edge  = (const int*)d_in[1];
    const int* focal = (const int*)d_in[5];

    const int N = in_sizes[0] / 100;   // 20000
    const int E = in_sizes[1] / 2;     // 320000
    const int B = in_sizes[5];         // 64
    const int EA = E + N;
    const int* srcArr = edge;
    const int* dstArr = edge + E;

    // ---- conversion table: all float inputs -> fp32 in ws ----
    const int idxs[NSEG] = {7,8,9,10,11,12,13,14,15,16,17,18,19,20,
                            35,36,37,38,39,40,41,42,43,44, 0, 6};
    float* base = (float*)d_ws;
    int* flag = (int*)base;            // base[0..15] reserved
    float* wf = base + 16;
    Tab tab;
    int off[NSEG];
    int o = 0;
    for (int i = 0; i < NSEG; i++) {
        tab.s[i].src = d_in[idxs[i]];
        tab.s[i].n   = in_sizes[idxs[i]];
        tab.s[i].off = o;
        off[i] = o;
        o += in_sizes[idxs[i]];
    }
    const float* aeW  = wf + off[0],  *aeb  = wf + off[1];
    const float* a1Wl = wf + off[2],  *a1bl = wf + off[3];
    const float* a1Wr = wf + off[4],  *a1br = wf + off[5];
    const float* a1att= wf + off[6],  *a1b  = wf + off[7];
    const float* a2Wl = wf + off[8],  *a2bl = wf + off[9];
    const float* a2Wr = wf + off[10], *a2br = wf + off[11];
    const float* a2att= wf + off[12], *a2b  = wf + off[13];
    const float* clW  = wf + off[14], *clb  = wf + off[15];
    const float* gWl  = wf + off[16], *gbl  = wf + off[17];
    const float* gWr  = wf + off[18], *gbr  = wf + off[19];
    const float* gatt = wf + off[20], *gb   = wf + off[21];
    const float* fcW  = wf + off[22], *fcb  = wf + off[23];
    const float* xf   = wf + off[24];
    const float* clf  = wf + off[25];

    // ---- remaining workspace ----
    float* p = wf + o;
    size_t N128 = (size_t)N * 128;
    float* ax = p;                  p += (size_t)N * 32;   // embed out
    float* fA = p;                  p += N128;             // xl (later xlg/xrg/gf)
    float* fB = p;                  p += N128;             // xr
    float* fC = p;                  p += N128;             // h / agent_features
    int* deg    = (int*)p;
    int* cursor = deg + N;
    int* offs   = cursor + N;       // N+1
    int* csr    = offs + N + 1;     // EA (src node ids)

    const int T = 256;
    // ---- dtype detect + convert ----
    k_detect<<<1, 256, 0, stream>>>((const unsigned short*)d_in[0], flag);
    k_convert<<<1024, 256, 0, stream>>>(tab, wf, flag);

    // ---- CSR build (shared by all 3 GAT layers) ----
    k_zero_int<<<(2 * N + T - 1) / T, T, 0, stream>>>(deg, 2 * N);
    k_count<<<(EA + T - 1) / T, T, 0, stream>>>(dstArr, E, N, deg);
    k_scan<<<1, 1024, 0, stream>>>(deg, offs, N);
    k_fill<<<(EA + T - 1) / T, T, 0, stream>>>(srcArr, dstArr, E, N, offs, cursor, csr);

    // ---- agent embedding: relu(x@aeW + aeb) ----
    k_lin<100, 32, 1, 32, 1><<<N / 32, 256, 0, stream>>>(xf, aeW, aeb, aeW, aeb, ax, ax);

    // ---- conv1 ----
    k_lin<32, 128, 2, 32, 0><<<N / 32, 256, 0, stream>>>(ax, a1Wl, a1bl, a1Wr, a1br, fA, fB);
    k_gat<4><<<N, 128, 0, stream>>>(fA, fB, a1att, offs, csr, a1b, fC);

    // ---- conv2 ----
    k_lin<128, 128, 2, 32, 0><<<N / 32, 256, 0, stream>>>(fC, a2Wl, a2bl, a2Wr, a2br, fA, fB);
    k_gat<4><<<N, 128, 0, stream>>>(fA, fB, a2att, offs, csr, a2b, fC);

    // ---- global graph (heads=1) ----
    float* xlg = fA;
    float* xrg = fA + (size_t)N * 32;
    float* gf  = fA + (size_t)N * 64;
    k_lin<128, 32, 2, 32, 0><<<N / 32, 256, 0, stream>>>(fC, gWl, gbl, gWr, gbr, xlg, xrg);
    k_gat_g<<<N, 64, 0, stream>>>(xlg, xrg, gatt, offs, csr, gb, gf);

    // ---- tail ----
    k_tail<<<B, 64, 0, stream>>>(gf, focal, clf, clW, clb, fcW, fcb, d_out, flag);
}

// Round 5
// 354.345 us; speedup vs baseline: 2.6738x; 1.0912x over previous
//
#include <hip/hip_runtime.h>
#include <hip/hip_bf16.h>
#include <math.h>

typedef __hip_bfloat16 bf16;
#define NEG_SLOPE 0.2f

// ================= dtype detection =================
__global__ void k_detect(const unsigned short* __restrict__ x, int* __restrict__ flag) {
    __shared__ int cnt;
    if (threadIdx.x == 0) cnt = 0;
    __syncthreads();
    int local = 0;
    for (int i = threadIdx.x; i < 2048; i += blockDim.x) {
        unsigned short w = x[2 * i];
        int e = (w >> 7) & 0xFF;
        if (e >= 0x90) local++;
    }
    atomicAdd(&cnt, local);
    __syncthreads();
    if (threadIdx.x == 0) flag[0] = (cnt > 100) ? 1 : 0;  // 1 => inputs are f32
}

#define NSEG 25
struct Seg { const void* src; int n; int off; };
struct Tab { Seg s[NSEG]; };

__global__ void k_convert(Tab tab, float* __restrict__ dst, const int* __restrict__ flag) {
    int f32mode = flag[0];
    for (int s = 0; s < NSEG; s++) {
        Seg sg = tab.s[s];
        for (int i = blockIdx.x * blockDim.x + threadIdx.x; i < sg.n;
             i += gridDim.x * blockDim.x) {
            float v = f32mode ? ((const float*)sg.src)[i]
                              : __bfloat162float(((const bf16*)sg.src)[i]);
            dst[sg.off + i] = v;
        }
    }
}

// ================= CSR build =================
__global__ void k_zero_int(int* p, int n) {
    int i = blockIdx.x * blockDim.x + threadIdx.x;
    if (i < n) p[i] = 0;
}

__global__ void k_count(const int* __restrict__ dstArr, int E, int N, int* __restrict__ deg) {
    int e = blockIdx.x * blockDim.x + threadIdx.x;
    int EA = E + N;
    if (e >= EA) return;
    int d = (e < E) ? dstArr[e] : (e - E);
    atomicAdd(&deg[d], 1);
}

__global__ void k_scan(const int* __restrict__ deg, int* __restrict__ offs, int n) {
    __shared__ int wsum[16];
    __shared__ int woff[16];
    __shared__ int stot;
    __shared__ int srun_s;
    int tid = threadIdx.x;
    int lane = tid & 63, wid = tid >> 6;
    if (tid == 0) srun_s = 0;
    __syncthreads();
    for (int base = 0; base < n; base += 1024) {
        int i = base + tid;
        int v = (i < n) ? deg[i] : 0;
        int x = v;
        #pragma unroll
        for (int o = 1; o < 64; o <<= 1) {
            int y = __shfl_up(x, o);
            if (lane >= o) x += y;
        }
        if (lane == 63) wsum[wid] = x;
        int run = srun_s;
        __syncthreads();
        if (wid == 0) {
            int w = (lane < 16) ? wsum[lane] : 0;
            int ws = w;
            #pragma unroll
            for (int o = 1; o < 16; o <<= 1) {
                int y = __shfl_up(ws, o);
                if (lane >= o) ws += y;
            }
            if (lane < 16) woff[lane] = ws - w;
            if (lane == 15) stot = ws;
        }
        __syncthreads();
        if (i < n) offs[i] = run + woff[wid] + x - v;  // exclusive
        if (tid == 0) srun_s = run + stot;
        __syncthreads();
    }
    if (threadIdx.x == 0) offs[n] = srun_s;
}

// csr stores SRC NODE IDS directly (self-loop => d itself)
__global__ void k_fill(const int* __restrict__ srcArr, const int* __restrict__ dstArr,
                       int E, int N, const int* __restrict__ offs,
                       int* __restrict__ cursor, int* __restrict__ csr) {
    int e = blockIdx.x * blockDim.x + threadIdx.x;
    int EA = E + N;
    if (e >= EA) return;
    int d, s;
    if (e < E) { d = dstArr[e]; s = srcArr[e]; } else { d = s = e - E; }
    int pos = atomicAdd(&cursor[d], 1);
    csr[offs[d] + pos] = s;
}

// ===== agent embedding: relu(x[N,100]@W[100,32]+b), x read natively ==========
__launch_bounds__(256)
__global__ void k_embed(const void* __restrict__ xraw, const float* __restrict__ W,
                        const float* __restrict__ bvec, float* __restrict__ out,
                        const int* __restrict__ flag) {
    constexpr int NT = 32, NTP = 36;
    __shared__ float xs[100 * NTP];
    int t = threadIdx.x, nb = blockIdx.x * NT;
    if (flag[0]) {
        const float4* x4 = (const float4*)xraw;
        for (int idx = t; idx < NT * 25; idx += 256) {
            int node = idx / 25, k4 = idx % 25;
            float4 v = x4[(size_t)(nb + node) * 25 + k4];
            xs[(k4 * 4 + 0) * NTP + node] = v.x;
            xs[(k4 * 4 + 1) * NTP + node] = v.y;
            xs[(k4 * 4 + 2) * NTP + node] = v.z;
            xs[(k4 * 4 + 3) * NTP + node] = v.w;
        }
    } else {
        const ushort4* xu = (const ushort4*)xraw;
        for (int idx = t; idx < NT * 25; idx += 256) {
            int node = idx / 25, k4 = idx % 25;
            ushort4 u = xu[(size_t)(nb + node) * 25 + k4];
            xs[(k4 * 4 + 0) * NTP + node] = __uint_as_float((unsigned)u.x << 16);
            xs[(k4 * 4 + 1) * NTP + node] = __uint_as_float((unsigned)u.y << 16);
            xs[(k4 * 4 + 2) * NTP + node] = __uint_as_float((unsigned)u.z << 16);
            xs[(k4 * 4 + 3) * NTP + node] = __uint_as_float((unsigned)u.w << 16);
        }
    }
    __syncthreads();
    int j = t & 31, g0 = t >> 5;  // 8 groups x 4 nodes
    float a0 = 0.f, a1 = 0.f, a2 = 0.f, a3 = 0.f;
    #pragma unroll 10
    for (int k = 0; k < 100; k++) {
        float w = W[k * 32 + j];
        const float4 xv = *(const float4*)&xs[k * NTP + g0 * 4];
        a0 += w * xv.x; a1 += w * xv.y; a2 += w * xv.z; a3 += w * xv.w;
    }
    float bj = bvec[j];
    out[(size_t)(nb + g0 * 4 + 0) * 32 + j] = fmaxf(a0 + bj, 0.f);
    out[(size_t)(nb + g0 * 4 + 1) * 32 + j] = fmaxf(a1 + bj, 0.f);
    out[(size_t)(nb + g0 * 4 + 2) * 32 + j] = fmaxf(a2 + bj, 0.f);
    out[(size_t)(nb + g0 * 4 + 3) * 32 + j] = fmaxf(a3 + bj, 0.f);
}

// ===== dual linear, both halves per thread share LDS reads ===================
template <int FIN, int FOUT, int NT>
__launch_bounds__(256)
__global__ void k_lin2(const float* __restrict__ x,
                       const float* __restrict__ Wl, const float* __restrict__ bl,
                       const float* __restrict__ Wr, const float* __restrict__ br,
                       float* __restrict__ outl, float* __restrict__ outr) {
    constexpr int NTP = NT + 4;
    constexpr int NG = 256 / FOUT;         // node groups across threads
    constexpr int GPT = (NT / 4) / NG;     // float4 groups per thread
    __shared__ float xs[FIN * NTP];
    int t = threadIdx.x, nb = blockIdx.x * NT;

    const float4* x4 = (const float4*)x;
    for (int idx = t; idx < NT * (FIN / 4); idx += 256) {
        int node = idx / (FIN / 4), k4 = idx % (FIN / 4);
        float4 v = x4[(size_t)(nb + node) * (FIN / 4) + k4];
        xs[(k4 * 4 + 0) * NTP + node] = v.x;
        xs[(k4 * 4 + 1) * NTP + node] = v.y;
        xs[(k4 * 4 + 2) * NTP + node] = v.z;
        xs[(k4 * 4 + 3) * NTP + node] = v.w;
    }
    __syncthreads();

    int j = t % FOUT, g0 = t / FOUT;
    float aL[GPT][4], aR[GPT][4];
    #pragma unroll
    for (int g = 0; g < GPT; g++)
        for (int c = 0; c < 4; c++) { aL[g][c] = 0.f; aR[g][c] = 0.f; }

    #pragma unroll 4
    for (int k = 0; k < FIN; k++) {
        float wl = Wl[(size_t)k * FOUT + j];
        float wr = Wr[(size_t)k * FOUT + j];
        #pragma unroll
        for (int g = 0; g < GPT; g++) {
            const float4 xv = *(const float4*)&xs[k * NTP + (g0 + g * NG) * 4];
            aL[g][0] += wl * xv.x; aL[g][1] += wl * xv.y;
            aL[g][2] += wl * xv.z; aL[g][3] += wl * xv.w;
            aR[g][0] += wr * xv.x; aR[g][1] += wr * xv.y;
            aR[g][2] += wr * xv.z; aR[g][3] += wr * xv.w;
        }
    }

    float blj = bl[j], brj = br[j];
    #pragma unroll
    for (int g = 0; g < GPT; g++) {
        int n0 = nb + (g0 + g * NG) * 4;
        #pragma unroll
        for (int c = 0; c < 4; c++) {
            outl[(size_t)(n0 + c) * FOUT + j] = aL[g][c] + blj;
            outr[(size_t)(n0 + c) * FOUT + j] = aR[g][c] + brj;
        }
    }
}

// ===== fused GAT H=4 (F=128): 1 wave per dst, float2 per lane ================
__launch_bounds__(256)
__global__ void k_gat4(const float2* __restrict__ xl2, const float2* __restrict__ xr2,
                       const float2* __restrict__ att2,
                       const int* __restrict__ offs, const int* __restrict__ csr,
                       const float2* __restrict__ bias2, float2* __restrict__ out2,
                       int N) {
    int wave = threadIdx.x >> 6, lane = threadIdx.x & 63;
    int d = blockIdx.x * 4 + wave;
    if (d >= N) return;
    int i0 = offs[d], i1 = offs[d + 1];
    float2 xrd = xr2[(size_t)d * 64 + lane];
    float2 av = att2[lane];
    float sm = 0.f;
    float accx = 0.f, accy = 0.f;

    auto proc = [&](float2 v) {
        float ux = v.x + xrd.x; ux = (ux > 0.f) ? ux : NEG_SLOPE * ux;
        float uy = v.y + xrd.y; uy = (uy > 0.f) ? uy : NEG_SLOPE * uy;
        float p = ux * av.x + uy * av.y;
        p += __shfl_xor(p, 8);
        p += __shfl_xor(p, 4);
        p += __shfl_xor(p, 2);
        p += __shfl_xor(p, 1);
        float w = __expf(fminf(p, 80.f));
        sm += w; accx += w * v.x; accy += w * v.y;
    };

    int i = i0;
    for (; i + 4 <= i1; i += 4) {
        int s0 = csr[i], s1 = csr[i + 1], s2 = csr[i + 2], s3 = csr[i + 3];
        float2 v0 = xl2[(size_t)s0 * 64 + lane];
        float2 v1 = xl2[(size_t)s1 * 64 + lane];
        float2 v2 = xl2[(size_t)s2 * 64 + lane];
        float2 v3 = xl2[(size_t)s3 * 64 + lane];
        proc(v0); proc(v1); proc(v2); proc(v3);
    }
    for (; i < i1; i++) proc(xl2[(size_t)csr[i] * 64 + lane]);

    float inv = 1.f / (sm + 1e-16f);
    float2 b = bias2[lane];
    float2 o;
    o.x = fmaxf(accx * inv + b.x, 0.f);
    o.y = fmaxf(accy * inv + b.y, 0.f);
    out2[(size_t)d * 64 + lane] = o;
}

// ===== fused GAT H=1 (F=32): 1 wave per dst, 4 edge-groups x 16 lanes ========
__launch_bounds__(256)
__global__ void k_gatg(const float2* __restrict__ xl2, const float2* __restrict__ xr2,
                       const float2* __restrict__ att2,
                       const int* __restrict__ offs, const int* __restrict__ csr,
                       const float2* __restrict__ bias2, float2* __restrict__ out2,
                       int N) {
    int wave = threadIdx.x >> 6, lane = threadIdx.x & 63;
    int d = blockIdx.x * 4 + wave;
    if (d >= N) return;
    int k = lane & 15, grp = lane >> 4;
    int i0 = offs[d], i1 = offs[d + 1];
    float2 xrd = xr2[(size_t)d * 16 + k];
    float2 av = att2[k];
    float sm = 0.f, accx = 0.f, accy = 0.f;

    for (int i = i0 + grp; i < i1; i += 4) {
        float2 v = xl2[(size_t)csr[i] * 16 + k];
        float ux = v.x + xrd.x; ux = (ux > 0.f) ? ux : NEG_SLOPE * ux;
        float uy = v.y + xrd.y; uy = (uy > 0.f) ? uy : NEG_SLOPE * uy;
        float p = ux * av.x + uy * av.y;
        p += __shfl_xor(p, 8);
        p += __shfl_xor(p, 4);
        p += __shfl_xor(p, 2);
        p += __shfl_xor(p, 1);
        float w = __expf(fminf(p, 80.f));
        sm += w; accx += w * v.x; accy += w * v.y;
    }
    // merge the 4 edge-groups (all lanes converged here)
    sm   += __shfl_xor(sm, 16);   sm   += __shfl_xor(sm, 32);
    accx += __shfl_xor(accx, 16); accx += __shfl_xor(accx, 32);
    accy += __shfl_xor(accy, 16); accy += __shfl_xor(accy, 32);
    if (grp == 0) {
        float inv = 1.f / (sm + 1e-16f);
        float2 b = bias2[k];
        float2 o;
        o.x = fmaxf(accx * inv + b.x, 0.f);
        o.y = fmaxf(accy * inv + b.y, 0.f);
        out2[(size_t)d * 16 + k] = o;
    }
}

// ================= tail =================
__global__ void k_tail(const float* __restrict__ gf, const int* __restrict__ focal,
                       const float* __restrict__ clf, const float* __restrict__ clW,
                       const float* __restrict__ clb, const float* __restrict__ fcW,
                       const float* __restrict__ fcb, void* __restrict__ out,
                       const int* __restrict__ flag) {
    int b = blockIdx.x;
    int t = threadIdx.x;
    __shared__ float comb[64];
    __shared__ float ssum[2];
    if (t < 2) {
        float s = 0.f;
        for (int l = 0; l < 50; l++) s += clf[(size_t)b * 100 + l * 2 + t];
        ssum[t] = s / 50.f;
    }
    if (t < 32) comb[t] = gf[(size_t)focal[b] * 32 + t];
    __syncthreads();
    if (t < 32) comb[32 + t] = ssum[0] * clW[t] + ssum[1] * clW[32 + t] + clb[t];
    __syncthreads();
    if (t < 60) {
        float acc = fcb[t];
        #pragma unroll 16
        for (int k = 0; k < 64; k++) acc += comb[k] * fcW[k * 60 + t];
        if (flag[0]) ((float*)out)[b * 60 + t] = acc;
        else ((bf16*)out)[b * 60 + t] = __float2bfloat16(acc);
    }
}

extern "C" void kernel_launch(void* const* d_in, const int* in_sizes, int n_in,
                              void* d_out, int out_size, void* d_ws, size_t ws_size,
                              hipStream_t stream) {
    const int* edge  = (const int*)d_in[1];
    const int* focal = (const int*)d_in[5];

    const int N = in_sizes[0] / 100;   // 20000
    const int E = in_sizes[1] / 2;     // 320000
    const int B = in_sizes[5];         // 64
    const int EA = E + N;
    const int* srcArr = edge;
    const int* dstArr = edge + E;

    // ---- conversion table: weights + centerlines -> fp32 in ws (x stays raw)
    const int idxs[NSEG] = {7,8,9,10,11,12,13,14,15,16,17,18,19,20,
                            35,36,37,38,39,40,41,42,43,44, 6};
    float* base = (float*)d_ws;
    int* flag = (int*)base;            // base[0..15] reserved
    float* wf = base + 16;
    Tab tab;
    int off[NSEG];
    int o = 0;
    for (int i = 0; i < NSEG; i++) {
        tab.s[i].src = d_in[idxs[i]];
        tab.s[i].n   = in_sizes[idxs[i]];
        tab.s[i].off = o;
        off[i] = o;
        o += in_sizes[idxs[i]];
    }
    const float* aeW  = wf + off[0],  *aeb  = wf + off[1];
    const float* a1Wl = wf + off[2],  *a1bl = wf + off[3];
    const float* a1Wr = wf + off[4],  *a1br = wf + off[5];
    const float* a1att= wf + off[6],  *a1b  = wf + off[7];
    const float* a2Wl = wf + off[8],  *a2bl = wf + off[9];
    const float* a2Wr = wf + off[10], *a2br = wf + off[11];
    const float* a2att= wf + off[12], *a2b  = wf + off[13];
    const float* clW  = wf + off[14], *clb  = wf + off[15];
    const float* gWl  = wf + off[16], *gbl  = wf + off[17];
    const float* gWr  = wf + off[18], *gbr  = wf + off[19];
    const float* gatt = wf + off[20], *gb   = wf + off[21];
    const float* fcW  = wf + off[22], *fcb  = wf + off[23];
    const float* clf  = wf + off[24];

    // ---- remaining workspace (all offsets even -> float2-aligned) ----
    float* p = wf + o + (o & 1);
    size_t N128 = (size_t)N * 128;
    float* ax = p;                  p += (size_t)N * 32;   // embed out
    float* fA = p;                  p += N128;             // xl (later xlg/xrg/gf)
    float* fB = p;                  p += N128;             // xr
    float* fC = p;                  p += N128;             // h / agent_features
    int* deg    = (int*)p;
    int* cursor = deg + N;
    int* offs   = cursor + N;       // N+1
    int* csr    = offs + N + 1;     // EA (src node ids)

    const int T = 256;
    // ---- dtype detect + convert ----
    k_detect<<<1, 256, 0, stream>>>((const unsigned short*)d_in[0], flag);
    k_convert<<<256, 256, 0, stream>>>(tab, wf, flag);

    // ---- CSR build (shared by all 3 GAT layers) ----
    k_zero_int<<<(2 * N + T - 1) / T, T, 0, stream>>>(deg, 2 * N);
    k_count<<<(EA + T - 1) / T, T, 0, stream>>>(dstArr, E, N, deg);
    k_scan<<<1, 1024, 0, stream>>>(deg, offs, N);
    k_fill<<<(EA + T - 1) / T, T, 0, stream>>>(srcArr, dstArr, E, N, offs, cursor, csr);

    // ---- agent embedding ----
    k_embed<<<N / 32, 256, 0, stream>>>(d_in[0], aeW, aeb, ax, flag);

    // ---- conv1 ----
    k_lin2<32, 128, 32><<<N / 32, 256, 0, stream>>>(ax, a1Wl, a1bl, a1Wr, a1br, fA, fB);
    k_gat4<<<(N + 3) / 4, 256, 0, stream>>>((const float2*)fA, (const float2*)fB,
                                            (const float2*)a1att, offs, csr,
                                            (const float2*)a1b, (float2*)fC, N);

    // ---- conv2 ----
    k_lin2<128, 128, 32><<<N / 32, 256, 0, stream>>>(fC, a2Wl, a2bl, a2Wr, a2br, fA, fB);
    k_gat4<<<(N + 3) / 4, 256, 0, stream>>>((const float2*)fA, (const float2*)fB,
                                            (const float2*)a2att, offs, csr,
                                            (const float2*)a2b, (float2*)fC, N);

    // ---- global graph (heads=1) ----
    float* xlg = fA;
    float* xrg = fA + (size_t)N * 32;
    float* gf  = fA + (size_t)N * 64;
    k_lin2<128, 32, 32><<<N / 32, 256, 0, stream>>>(fC, gWl, gbl, gWr, gbr, xlg, xrg);
    k_gatg<<<(N + 3) / 4, 256, 0, stream>>>((const float2*)xlg, (const float2*)xrg,
                                            (const float2*)gatt, offs, csr,
                                            (const float2*)gb, (float2*)gf, N);

    // ---- tail ----
    k_tail<<<B, 64, 0, stream>>>(gf, focal, clf, clW, clb, fcW, fcb, d_out, flag);
}

// Round 6
// 335.565 us; speedup vs baseline: 2.8234x; 1.0560x over previous
//
#include <hip/hip_runtime.h>
#include <hip/hip_bf16.h>
#include <hip/hip_fp16.h>
#include <math.h>

typedef __hip_bfloat16 bf16;
#define NEG_SLOPE 0.2f

// ====== dtype detect (block 0) + zero deg/cursor (all blocks) ================
__global__ void k_detect_zero(const unsigned short* __restrict__ x, int* __restrict__ flag,
                              int* __restrict__ deg, int n) {
    for (int i = blockIdx.x * blockDim.x + threadIdx.x; i < n; i += gridDim.x * blockDim.x)
        deg[i] = 0;
    if (blockIdx.x == 0) {
        __shared__ int cnt;
        if (threadIdx.x == 0) cnt = 0;
        __syncthreads();
        int local = 0;
        for (int i = threadIdx.x; i < 2048; i += blockDim.x) {
            unsigned short w = x[2 * i];
            int e = (w >> 7) & 0xFF;
            if (e >= 0x90) local++;
        }
        atomicAdd(&cnt, local);
        __syncthreads();
        if (threadIdx.x == 0) flag[0] = (cnt > 100) ? 1 : 0;  // 1 => inputs are f32
    }
}

#define NSEG 25
struct Seg { const void* src; int n; int off; };
struct Tab { Seg s[NSEG]; };

// ====== convert weights to fp32 + count degrees ==============================
__global__ void k_convert(Tab tab, float* __restrict__ dst, const int* __restrict__ flag,
                          const int* __restrict__ dstArr, int E, int N,
                          int* __restrict__ deg) {
    int f32mode = flag[0];
    int gid = blockIdx.x * blockDim.x + threadIdx.x;
    int gsz = gridDim.x * blockDim.x;
    for (int s = 0; s < NSEG; s++) {
        Seg sg = tab.s[s];
        for (int i = gid; i < sg.n; i += gsz) {
            float v = f32mode ? ((const float*)sg.src)[i]
                              : __bfloat162float(((const bf16*)sg.src)[i]);
            dst[sg.off + i] = v;
        }
    }
    int EA = E + N;
    for (int e = gid; e < EA; e += gsz) {
        int d = (e < E) ? dstArr[e] : (e - E);
        atomicAdd(&deg[d], 1);
    }
}

// ================= CSR scan + fill =================
__global__ void k_scan(const int* __restrict__ deg, int* __restrict__ offs, int n) {
    __shared__ int wsum[16];
    __shared__ int woff[16];
    __shared__ int stot;
    __shared__ int srun_s;
    int tid = threadIdx.x;
    int lane = tid & 63, wid = tid >> 6;
    if (tid == 0) srun_s = 0;
    __syncthreads();
    for (int base = 0; base < n; base += 1024) {
        int i = base + tid;
        int v = (i < n) ? deg[i] : 0;
        int x = v;
        #pragma unroll
        for (int o = 1; o < 64; o <<= 1) {
            int y = __shfl_up(x, o);
            if (lane >= o) x += y;
        }
        if (lane == 63) wsum[wid] = x;
        int run = srun_s;
        __syncthreads();
        if (wid == 0) {
            int w = (lane < 16) ? wsum[lane] : 0;
            int ws = w;
            #pragma unroll
            for (int o = 1; o < 16; o <<= 1) {
                int y = __shfl_up(ws, o);
                if (lane >= o) ws += y;
            }
            if (lane < 16) woff[lane] = ws - w;
            if (lane == 15) stot = ws;
        }
        __syncthreads();
        if (i < n) offs[i] = run + woff[wid] + x - v;  // exclusive
        if (tid == 0) srun_s = run + stot;
        __syncthreads();
    }
    if (threadIdx.x == 0) offs[n] = srun_s;
}

// csr stores SRC NODE IDS directly (self-loop => d itself)
__global__ void k_fill(const int* __restrict__ srcArr, const int* __restrict__ dstArr,
                       int E, int N, const int* __restrict__ offs,
                       int* __restrict__ cursor, int* __restrict__ csr) {
    int e = blockIdx.x * blockDim.x + threadIdx.x;
    int EA = E + N;
    if (e >= EA) return;
    int d, s;
    if (e < E) { d = dstArr[e]; s = srcArr[e]; } else { d = s = e - E; }
    int pos = atomicAdd(&cursor[d], 1);
    csr[offs[d] + pos] = s;
}

// ===== agent embedding: relu(x[N,100]@W[100,32]+b), x read natively ==========
__launch_bounds__(256)
__global__ void k_embed(const void* __restrict__ xraw, const float* __restrict__ W,
                        const float* __restrict__ bvec, float* __restrict__ out,
                        const int* __restrict__ flag) {
    constexpr int NT = 32, NTP = 36;
    __shared__ float xs[100 * NTP];
    int t = threadIdx.x, nb = blockIdx.x * NT;
    if (flag[0]) {
        const float4* x4 = (const float4*)xraw;
        for (int idx = t; idx < NT * 25; idx += 256) {
            int node = idx / 25, k4 = idx % 25;
            float4 v = x4[(size_t)(nb + node) * 25 + k4];
            xs[(k4 * 4 + 0) * NTP + node] = v.x;
            xs[(k4 * 4 + 1) * NTP + node] = v.y;
            xs[(k4 * 4 + 2) * NTP + node] = v.z;
            xs[(k4 * 4 + 3) * NTP + node] = v.w;
        }
    } else {
        const ushort4* xu = (const ushort4*)xraw;
        for (int idx = t; idx < NT * 25; idx += 256) {
            int node = idx / 25, k4 = idx % 25;
            ushort4 u = xu[(size_t)(nb + node) * 25 + k4];
            xs[(k4 * 4 + 0) * NTP + node] = __uint_as_float((unsigned)u.x << 16);
            xs[(k4 * 4 + 1) * NTP + node] = __uint_as_float((unsigned)u.y << 16);
            xs[(k4 * 4 + 2) * NTP + node] = __uint_as_float((unsigned)u.z << 16);
            xs[(k4 * 4 + 3) * NTP + node] = __uint_as_float((unsigned)u.w << 16);
        }
    }
    __syncthreads();
    int j = t & 31, g0 = t >> 5;  // 8 groups x 4 nodes
    float a0 = 0.f, a1 = 0.f, a2 = 0.f, a3 = 0.f;
    #pragma unroll 10
    for (int k = 0; k < 100; k++) {
        float w = W[k * 32 + j];
        const float4 xv = *(const float4*)&xs[k * NTP + g0 * 4];
        a0 += w * xv.x; a1 += w * xv.y; a2 += w * xv.z; a3 += w * xv.w;
    }
    float bj = bvec[j];
    out[(size_t)(nb + g0 * 4 + 0) * 32 + j] = fmaxf(a0 + bj, 0.f);
    out[(size_t)(nb + g0 * 4 + 1) * 32 + j] = fmaxf(a1 + bj, 0.f);
    out[(size_t)(nb + g0 * 4 + 2) * 32 + j] = fmaxf(a2 + bj, 0.f);
    out[(size_t)(nb + g0 * 4 + 3) * 32 + j] = fmaxf(a3 + bj, 0.f);
}

// ===== dual linear FOUT=128, 2 W-cols/thread; xl->fp16, xr->fp32 =============
template <int FIN, int NT>
__launch_bounds__(256)
__global__ void k_lin2w(const float* __restrict__ x,
                        const float* __restrict__ Wl, const float* __restrict__ bl,
                        const float* __restrict__ Wr, const float* __restrict__ br,
                        __half* __restrict__ outl, float* __restrict__ outr) {
    constexpr int NTP = NT + 4;
    constexpr int GPT = (NT / 4) / 4;      // float4 groups per thread (4 g0 groups)
    __shared__ float xs[FIN * NTP];
    int t = threadIdx.x, nb = blockIdx.x * NT;

    const float4* x4 = (const float4*)x;
    for (int idx = t; idx < NT * (FIN / 4); idx += 256) {
        int node = idx / (FIN / 4), k4 = idx % (FIN / 4);
        float4 v = x4[(size_t)(nb + node) * (FIN / 4) + k4];
        xs[(k4 * 4 + 0) * NTP + node] = v.x;
        xs[(k4 * 4 + 1) * NTP + node] = v.y;
        xs[(k4 * 4 + 2) * NTP + node] = v.z;
        xs[(k4 * 4 + 3) * NTP + node] = v.w;
    }
    __syncthreads();

    int j = t & 63, g0 = t >> 6;           // cols j and j+64
    float aL0[GPT][4], aL1[GPT][4], aR0[GPT][4], aR1[GPT][4];
    #pragma unroll
    for (int g = 0; g < GPT; g++)
        #pragma unroll
        for (int c = 0; c < 4; c++) { aL0[g][c]=0.f; aL1[g][c]=0.f; aR0[g][c]=0.f; aR1[g][c]=0.f; }

    #pragma unroll 4
    for (int k = 0; k < FIN; k++) {
        float wl0 = Wl[(size_t)k * 128 + j];
        float wl1 = Wl[(size_t)k * 128 + j + 64];
        float wr0 = Wr[(size_t)k * 128 + j];
        float wr1 = Wr[(size_t)k * 128 + j + 64];
        #pragma unroll
        for (int g = 0; g < GPT; g++) {
            const float4 xv = *(const float4*)&xs[k * NTP + (g0 + g * 4) * 4];
            aL0[g][0] += wl0 * xv.x; aL0[g][1] += wl0 * xv.y; aL0[g][2] += wl0 * xv.z; aL0[g][3] += wl0 * xv.w;
            aL1[g][0] += wl1 * xv.x; aL1[g][1] += wl1 * xv.y; aL1[g][2] += wl1 * xv.z; aL1[g][3] += wl1 * xv.w;
            aR0[g][0] += wr0 * xv.x; aR0[g][1] += wr0 * xv.y; aR0[g][2] += wr0 * xv.z; aR0[g][3] += wr0 * xv.w;
            aR1[g][0] += wr1 * xv.x; aR1[g][1] += wr1 * xv.y; aR1[g][2] += wr1 * xv.z; aR1[g][3] += wr1 * xv.w;
        }
    }

    float bl0 = bl[j], bl1 = bl[j + 64], br0 = br[j], br1 = br[j + 64];
    #pragma unroll
    for (int g = 0; g < GPT; g++) {
        int n0 = nb + (g0 + g * 4) * 4;
        #pragma unroll
        for (int c = 0; c < 4; c++) {
            size_t row = (size_t)(n0 + c) * 128;
            outl[row + j]      = __float2half(aL0[g][c] + bl0);
            outl[row + j + 64] = __float2half(aL1[g][c] + bl1);
            outr[row + j]      = aR0[g][c] + br0;
            outr[row + j + 64] = aR1[g][c] + br1;
        }
    }
}

// ===== dual linear FIN=128, FOUT=32 (global layer); xl->fp16, xr->fp32 =======
__launch_bounds__(256)
__global__ void k_ling(const float* __restrict__ x,
                       const float* __restrict__ Wl, const float* __restrict__ bl,
                       const float* __restrict__ Wr, const float* __restrict__ br,
                       __half* __restrict__ outl, float* __restrict__ outr) {
    constexpr int NT = 32, NTP = 36, FIN = 128;
    __shared__ float xs[FIN * NTP];
    int t = threadIdx.x, nb = blockIdx.x * NT;

    const float4* x4 = (const float4*)x;
    for (int idx = t; idx < NT * 32; idx += 256) {
        int node = idx >> 5, k4 = idx & 31;
        float4 v = x4[(size_t)(nb + node) * 32 + k4];
        xs[(k4 * 4 + 0) * NTP + node] = v.x;
        xs[(k4 * 4 + 1) * NTP + node] = v.y;
        xs[(k4 * 4 + 2) * NTP + node] = v.z;
        xs[(k4 * 4 + 3) * NTP + node] = v.w;
    }
    __syncthreads();

    int j = t & 31, g0 = t >> 5;  // 8 groups x 4 nodes
    float aL[4], aR[4];
    #pragma unroll
    for (int c = 0; c < 4; c++) { aL[c] = 0.f; aR[c] = 0.f; }

    #pragma unroll 4
    for (int k = 0; k < FIN; k++) {
        float wl = Wl[(size_t)k * 32 + j];
        float wr = Wr[(size_t)k * 32 + j];
        const float4 xv = *(const float4*)&xs[k * NTP + g0 * 4];
        aL[0] += wl * xv.x; aL[1] += wl * xv.y; aL[2] += wl * xv.z; aL[3] += wl * xv.w;
        aR[0] += wr * xv.x; aR[1] += wr * xv.y; aR[2] += wr * xv.z; aR[3] += wr * xv.w;
    }

    float blj = bl[j], brj = br[j];
    #pragma unroll
    for (int c = 0; c < 4; c++) {
        size_t row = (size_t)(nb + g0 * 4 + c) * 32;
        outl[row + j] = __float2half(aL[c] + blj);
        outr[row + j] = aR[c] + brj;
    }
}

// ===== fused GAT H=4 (F=128): 1 wave per dst; xl fp16, xr fp32 ===============
__launch_bounds__(256)
__global__ void k_gat4(const __half2* __restrict__ xl2, const float2* __restrict__ xr2,
                       const float2* __restrict__ att2,
                       const int* __restrict__ offs, const int* __restrict__ csr,
                       const float2* __restrict__ bias2, float2* __restrict__ out2,
                       int N) {
    int wave = threadIdx.x >> 6, lane = threadIdx.x & 63;
    int d = blockIdx.x * 4 + wave;
    if (d >= N) return;
    int i0 = offs[d], i1 = offs[d + 1];
    float2 xrd = xr2[(size_t)d * 64 + lane];
    float2 av = att2[lane];
    float sm = 0.f, accx = 0.f, accy = 0.f;

    auto proc = [&](__half2 vh) {
        float2 v = __half22float2(vh);
        float ux = v.x + xrd.x; ux = (ux > 0.f) ? ux : NEG_SLOPE * ux;
        float uy = v.y + xrd.y; uy = (uy > 0.f) ? uy : NEG_SLOPE * uy;
        float p = ux * av.x + uy * av.y;
        p += __shfl_xor(p, 8);
        p += __shfl_xor(p, 4);
        p += __shfl_xor(p, 2);
        p += __shfl_xor(p, 1);
        float w = __expf(fminf(p, 80.f));
        sm += w; accx += w * v.x; accy += w * v.y;
    };

    int i = i0;
    for (; i + 4 <= i1; i += 4) {
        int s0 = csr[i], s1 = csr[i + 1], s2 = csr[i + 2], s3 = csr[i + 3];
        __half2 v0 = xl2[(size_t)s0 * 64 + lane];
        __half2 v1 = xl2[(size_t)s1 * 64 + lane];
        __half2 v2 = xl2[(size_t)s2 * 64 + lane];
        __half2 v3 = xl2[(size_t)s3 * 64 + lane];
        proc(v0); proc(v1); proc(v2); proc(v3);
    }
    for (; i < i1; i++) proc(xl2[(size_t)csr[i] * 64 + lane]);

    float inv = 1.f / (sm + 1e-16f);
    float2 b = bias2[lane];
    float2 o;
    o.x = fmaxf(accx * inv + b.x, 0.f);
    o.y = fmaxf(accy * inv + b.y, 0.f);
    out2[(size_t)d * 64 + lane] = o;
}

// ===== fused GAT H=1 (F=32): 1 wave per dst, 4 edge-groups x 16 lanes ========
__launch_bounds__(256)
__global__ void k_gatg(const __half2* __restrict__ xl2, const float2* __restrict__ xr2,
                       const float2* __restrict__ att2,
                       const int* __restrict__ offs, const int* __restrict__ csr,
                       const float2* __restrict__ bias2, float2* __restrict__ out2,
                       int N) {
    int wave = threadIdx.x >> 6, lane = threadIdx.x & 63;
    int d = blockIdx.x * 4 + wave;
    if (d >= N) return;
    int k = lane & 15, grp = lane >> 4;
    int i0 = offs[d], i1 = offs[d + 1];
    float2 xrd = xr2[(size_t)d * 16 + k];
    float2 av = att2[k];
    float sm = 0.f, accx = 0.f, accy = 0.f;

    for (int i = i0 + grp; i < i1; i += 4) {
        float2 v = __half22float2(xl2[(size_t)csr[i] * 16 + k]);
        float ux = v.x + xrd.x; ux = (ux > 0.f) ? ux : NEG_SLOPE * ux;
        float uy = v.y + xrd.y; uy = (uy > 0.f) ? uy : NEG_SLOPE * uy;
        float p = ux * av.x + uy * av.y;
        p += __shfl_xor(p, 8);
        p += __shfl_xor(p, 4);
        p += __shfl_xor(p, 2);
        p += __shfl_xor(p, 1);
        float w = __expf(fminf(p, 80.f));
        sm += w; accx += w * v.x; accy += w * v.y;
    }
    sm   += __shfl_xor(sm, 16);   sm   += __shfl_xor(sm, 32);
    accx += __shfl_xor(accx, 16); accx += __shfl_xor(accx, 32);
    accy += __shfl_xor(accy, 16); accy += __shfl_xor(accy, 32);
    if (grp == 0) {
        float inv = 1.f / (sm + 1e-16f);
        float2 b = bias2[k];
        float2 o;
        o.x = fmaxf(accx * inv + b.x, 0.f);
        o.y = fmaxf(accy * inv + b.y, 0.f);
        out2[(size_t)d * 16 + k] = o;
    }
}

// ================= tail =================
__global__ void k_tail(const float* __restrict__ gf, const int* __restrict__ focal,
                       const float* __restrict__ clf, const float* __restrict__ clW,
                       const float* __restrict__ clb, const float* __restrict__ fcW,
                       const float* __restrict__ fcb, void* __restrict__ out,
                       const int* __restrict__ flag) {
    int b = blockIdx.x;
    int t = threadIdx.x;
    __shared__ float comb[64];
    __shared__ float ssum[2];
    if (t < 2) {
        float s = 0.f;
        for (int l = 0; l < 50; l++) s += clf[(size_t)b * 100 + l * 2 + t];
        ssum[t] = s / 50.f;
    }
    if (t < 32) comb[t] = gf[(size_t)focal[b] * 32 + t];
    __syncthreads();
    if (t < 32) comb[32 + t] = ssum[0] * clW[t] + ssum[1] * clW[32 + t] + clb[t];
    __syncthreads();
    if (t < 60) {
        float acc = fcb[t];
        #pragma unroll 16
        for (int k = 0; k < 64; k++) acc += comb[k] * fcW[k * 60 + t];
        if (flag[0]) ((float*)out)[b * 60 + t] = acc;
        else ((bf16*)out)[b * 60 + t] = __float2bfloat16(acc);
    }
}

extern "C" void kernel_launch(void* const* d_in, const int* in_sizes, int n_in,
                              void* d_out, int out_size, void* d_ws, size_t ws_size,
                              hipStream_t stream) {
    const int* edge  = (const int*)d_in[1];
    const int* focal = (const int*)d_in[5];

    const int N = in_sizes[0] / 100;   // 20000
    const int E = in_sizes[1] / 2;     // 320000
    const int B = in_sizes[5];         // 64
    const int EA = E + N;
    const int* srcArr = edge;
    const int* dstArr = edge + E;

    // ---- conversion table: weights + centerlines -> fp32 in ws (x stays raw)
    const int idxs[NSEG] = {7,8,9,10,11,12,13,14,15,16,17,18,19,20,
                            35,36,37,38,39,40,41,42,43,44, 6};
    float* base = (float*)d_ws;
    int* flag = (int*)base;            // base[0..15] reserved
    float* wf = base + 16;
    Tab tab;
    int off[NSEG];
    int o = 0;
    for (int i = 0; i < NSEG; i++) {
        tab.s[i].src = d_in[idxs[i]];
        tab.s[i].n   = in_sizes[idxs[i]];
        tab.s[i].off = o;
        off[i] = o;
        o += in_sizes[idxs[i]];
    }
    const float* aeW  = wf + off[0],  *aeb  = wf + off[1];
    const float* a1Wl = wf + off[2],  *a1bl = wf + off[3];
    const float* a1Wr = wf + off[4],  *a1br = wf + off[5];
    const float* a1att= wf + off[6],  *a1b  = wf + off[7];
    const float* a2Wl = wf + off[8],  *a2bl = wf + off[9];
    const float* a2Wr = wf + off[10], *a2br = wf + off[11];
    const float* a2att= wf + off[12], *a2b  = wf + off[13];
    const float* clW  = wf + off[14], *clb  = wf + off[15];
    const float* gWl  = wf + off[16], *gbl  = wf + off[17];
    const float* gWr  = wf + off[18], *gbr  = wf + off[19];
    const float* gatt = wf + off[20], *gb   = wf + off[21];
    const float* fcW  = wf + off[22], *fcb  = wf + off[23];
    const float* clf  = wf + off[24];

    // ---- remaining workspace (keep float2/half2 alignment) ----
    float* p = wf + o + (o & 1);
    size_t N128 = (size_t)N * 128;
    float* ax  = p;                 p += (size_t)N * 32;    // embed out (fp32)
    __half* hxl = (__half*)p;       p += (size_t)N * 64;    // xl fp16 [N,128] (or [N,32] global)
    float* fB  = p;                 p += N128;              // xr fp32 (global: xrg + gf)
    float* fC  = p;                 p += N128;              // h / agent_features fp32
    int* deg    = (int*)p;
    int* cursor = deg + N;
    int* offs   = cursor + N;       // N+1
    int* csr    = offs + N + 1;     // EA (src node ids)

    const int T = 256;
    // ---- detect + zero deg/cursor ----
    k_detect_zero<<<64, 256, 0, stream>>>((const unsigned short*)d_in[0], flag, deg, 2 * N);
    // ---- convert weights + count degrees ----
    k_convert<<<256, 256, 0, stream>>>(tab, wf, flag, dstArr, E, N, deg);
    k_scan<<<1, 1024, 0, stream>>>(deg, offs, N);
    k_fill<<<(EA + T - 1) / T, T, 0, stream>>>(srcArr, dstArr, E, N, offs, cursor, csr);

    // ---- agent embedding ----
    k_embed<<<N / 32, 256, 0, stream>>>(d_in[0], aeW, aeb, ax, flag);

    // ---- conv1 ----
    k_lin2w<32, 32><<<N / 32, 256, 0, stream>>>(ax, a1Wl, a1bl, a1Wr, a1br, hxl, fB);
    k_gat4<<<(N + 3) / 4, 256, 0, stream>>>((const __half2*)hxl, (const float2*)fB,
                                            (const float2*)a1att, offs, csr,
                                            (const float2*)a1b, (float2*)fC, N);

    // ---- conv2 ----
    k_lin2w<128, 32><<<N / 32, 256, 0, stream>>>(fC, a2Wl, a2bl, a2Wr, a2br, hxl, fB);
    k_gat4<<<(N + 3) / 4, 256, 0, stream>>>((const __half2*)hxl, (const float2*)fB,
                                            (const float2*)a2att, offs, csr,
                                            (const float2*)a2b, (float2*)fC, N);

    // ---- global graph (heads=1) ----
    float* xrg = fB;
    float* gf  = fB + (size_t)N * 32;
    k_ling<<<N / 32, 256, 0, stream>>>(fC, gWl, gbl, gWr, gbr, hxl, xrg);
    k_gatg<<<(N + 3) / 4, 256, 0, stream>>>((const __half2*)hxl, (const float2*)xrg,
                                            (const float2*)gatt, offs, csr,
                                            (const float2*)gb, (float2*)gf, N);

    // ---- tail ----
    k_tail<<<B, 64, 0, stream>>>(gf, focal, clf, clW, clb, fcW, fcb, d_out, flag);
}

// Round 7
// 316.843 us; speedup vs baseline: 2.9903x; 1.0591x over previous
//
#include <hip/hip_runtime.h>
#include <hip/hip_bf16.h>
#include <hip/hip_fp16.h>
#include <math.h>

typedef __hip_bfloat16 bf16;
#define NEG_SLOPE 0.2f

// ====== dtype detect (block 0) + zero deg/cursor (all blocks) ================
__global__ void k_detect_zero(const unsigned short* __restrict__ x, int* __restrict__ flag,
                              int* __restrict__ deg, int n) {
    for (int i = blockIdx.x * blockDim.x + threadIdx.x; i < n; i += gridDim.x * blockDim.x)
        deg[i] = 0;
    if (blockIdx.x == 0) {
        __shared__ int cnt;
        if (threadIdx.x == 0) cnt = 0;
        __syncthreads();
        int local = 0;
        for (int i = threadIdx.x; i < 2048; i += blockDim.x) {
            unsigned short w = x[2 * i];
            int e = (w >> 7) & 0xFF;
            if (e >= 0x90) local++;
        }
        atomicAdd(&cnt, local);
        __syncthreads();
        if (threadIdx.x == 0) flag[0] = (cnt > 100) ? 1 : 0;  // 1 => inputs are f32
    }
}

#define NSEG 25
struct Seg { const void* src; int n; int off; };
struct Tab { Seg s[NSEG]; };

// ====== convert weights to fp32 + count degrees ==============================
__global__ void k_convert(Tab tab, float* __restrict__ dst, const int* __restrict__ flag,
                          const int* __restrict__ dstArr, int E, int N,
                          int* __restrict__ deg) {
    int f32mode = flag[0];
    int gid = blockIdx.x * blockDim.x + threadIdx.x;
    int gsz = gridDim.x * blockDim.x;
    for (int s = 0; s < NSEG; s++) {
        Seg sg = tab.s[s];
        for (int i = gid; i < sg.n; i += gsz) {
            float v = f32mode ? ((const float*)sg.src)[i]
                              : __bfloat162float(((const bf16*)sg.src)[i]);
            dst[sg.off + i] = v;
        }
    }
    int EA = E + N;
    for (int e = gid; e < EA; e += gsz) {
        int d = (e < E) ? dstArr[e] : (e - E);
        atomicAdd(&deg[d], 1);
    }
}

// ====== parallel 3-phase exclusive scan ======================================
__launch_bounds__(1024)
__global__ void k_scan1(const int* __restrict__ deg, int* __restrict__ offs,
                        int* __restrict__ bsum, int n) {
    __shared__ int ws[16];
    int i = blockIdx.x * 1024 + threadIdx.x;
    int lane = threadIdx.x & 63, wid = threadIdx.x >> 6;
    int v = (i < n) ? deg[i] : 0;
    int x = v;
    #pragma unroll
    for (int o = 1; o < 64; o <<= 1) {
        int y = __shfl_up(x, o);
        if (lane >= o) x += y;
    }
    if (lane == 63) ws[wid] = x;
    __syncthreads();
    if (wid == 0) {
        int w = (lane < 16) ? ws[lane] : 0;
        int s = w;
        #pragma unroll
        for (int o = 1; o < 16; o <<= 1) {
            int y = __shfl_up(s, o);
            if (lane >= o) s += y;
        }
        if (lane < 16) ws[lane] = s - w;   // exclusive wave offsets
        if (lane == 15) bsum[blockIdx.x] = s;  // block total
    }
    __syncthreads();
    if (i < n) offs[i] = ws[wid] + x - v;  // block-local exclusive
}

__global__ void k_scan2(const int* __restrict__ bsum, int* __restrict__ bpref,
                        int* __restrict__ offs, int n, int nb) {
    int lane = threadIdx.x;  // 64
    int v = (lane < nb) ? bsum[lane] : 0;
    int x = v;
    #pragma unroll
    for (int o = 1; o < 64; o <<= 1) {
        int y = __shfl_up(x, o);
        if (lane >= o) x += y;
    }
    if (lane < nb) bpref[lane] = x - v;
    if (lane == nb - 1) offs[n] = x;  // grand total
}

__launch_bounds__(1024)
__global__ void k_addpref(int* __restrict__ offs, const int* __restrict__ bpref, int n) {
    int i = blockIdx.x * 1024 + threadIdx.x;
    if (i < n) offs[i] += bpref[i >> 10];
}

// csr stores SRC NODE IDS directly (self-loop => d itself)
__global__ void k_fill(const int* __restrict__ srcArr, const int* __restrict__ dstArr,
                       int E, int N, const int* __restrict__ offs,
                       int* __restrict__ cursor, int* __restrict__ csr) {
    int e = blockIdx.x * blockDim.x + threadIdx.x;
    int EA = E + N;
    if (e >= EA) return;
    int d, s;
    if (e < E) { d = dstArr[e]; s = srcArr[e]; } else { d = s = e - E; }
    int pos = atomicAdd(&cursor[d], 1);
    csr[offs[d] + pos] = s;
}

// ===== agent embedding: relu(x[N,100]@W[100,32]+b), x read natively ==========
__launch_bounds__(256)
__global__ void k_embed(const void* __restrict__ xraw, const float* __restrict__ W,
                        const float* __restrict__ bvec, float* __restrict__ out,
                        const int* __restrict__ flag) {
    constexpr int NT = 32, NTP = 36;
    __shared__ float xs[100 * NTP];
    int t = threadIdx.x, nb = blockIdx.x * NT;
    if (flag[0]) {
        const float4* x4 = (const float4*)xraw;
        for (int idx = t; idx < NT * 25; idx += 256) {
            int node = idx / 25, k4 = idx % 25;
            float4 v = x4[(size_t)(nb + node) * 25 + k4];
            xs[(k4 * 4 + 0) * NTP + node] = v.x;
            xs[(k4 * 4 + 1) * NTP + node] = v.y;
            xs[(k4 * 4 + 2) * NTP + node] = v.z;
            xs[(k4 * 4 + 3) * NTP + node] = v.w;
        }
    } else {
        const ushort4* xu = (const ushort4*)xraw;
        for (int idx = t; idx < NT * 25; idx += 256) {
            int node = idx / 25, k4 = idx % 25;
            ushort4 u = xu[(size_t)(nb + node) * 25 + k4];
            xs[(k4 * 4 + 0) * NTP + node] = __uint_as_float((unsigned)u.x << 16);
            xs[(k4 * 4 + 1) * NTP + node] = __uint_as_float((unsigned)u.y << 16);
            xs[(k4 * 4 + 2) * NTP + node] = __uint_as_float((unsigned)u.z << 16);
            xs[(k4 * 4 + 3) * NTP + node] = __uint_as_float((unsigned)u.w << 16);
        }
    }
    __syncthreads();
    int j = t & 31, g0 = t >> 5;  // 8 groups x 4 nodes
    float a0 = 0.f, a1 = 0.f, a2 = 0.f, a3 = 0.f;
    #pragma unroll 10
    for (int k = 0; k < 100; k++) {
        float w = W[k * 32 + j];
        const float4 xv = *(const float4*)&xs[k * NTP + g0 * 4];
        a0 += w * xv.x; a1 += w * xv.y; a2 += w * xv.z; a3 += w * xv.w;
    }
    float bj = bvec[j];
    out[(size_t)(nb + g0 * 4 + 0) * 32 + j] = fmaxf(a0 + bj, 0.f);
    out[(size_t)(nb + g0 * 4 + 1) * 32 + j] = fmaxf(a1 + bj, 0.f);
    out[(size_t)(nb + g0 * 4 + 2) * 32 + j] = fmaxf(a2 + bj, 0.f);
    out[(size_t)(nb + g0 * 4 + 3) * 32 + j] = fmaxf(a3 + bj, 0.f);
}

// ===== dual linear FOUT=128, 2 W-cols/thread; xl->fp16, xr->fp32 =============
template <int FIN, int NT>
__launch_bounds__(256)
__global__ void k_lin2w(const float* __restrict__ x,
                        const float* __restrict__ Wl, const float* __restrict__ bl,
                        const float* __restrict__ Wr, const float* __restrict__ br,
                        __half* __restrict__ outl, float* __restrict__ outr) {
    constexpr int NTP = NT + 4;
    constexpr int GPT = (NT / 4) / 4;      // float4 groups per thread (4 g0 groups)
    __shared__ float xs[FIN * NTP];
    int t = threadIdx.x, nb = blockIdx.x * NT;

    const float4* x4 = (const float4*)x;
    for (int idx = t; idx < NT * (FIN / 4); idx += 256) {
        int node = idx / (FIN / 4), k4 = idx % (FIN / 4);
        float4 v = x4[(size_t)(nb + node) * (FIN / 4) + k4];
        xs[(k4 * 4 + 0) * NTP + node] = v.x;
        xs[(k4 * 4 + 1) * NTP + node] = v.y;
        xs[(k4 * 4 + 2) * NTP + node] = v.z;
        xs[(k4 * 4 + 3) * NTP + node] = v.w;
    }
    __syncthreads();

    int j = t & 63, g0 = t >> 6;           // cols j and j+64
    float aL0[GPT][4], aL1[GPT][4], aR0[GPT][4], aR1[GPT][4];
    #pragma unroll
    for (int g = 0; g < GPT; g++)
        #pragma unroll
        for (int c = 0; c < 4; c++) { aL0[g][c]=0.f; aL1[g][c]=0.f; aR0[g][c]=0.f; aR1[g][c]=0.f; }

    #pragma unroll 4
    for (int k = 0; k < FIN; k++) {
        float wl0 = Wl[(size_t)k * 128 + j];
        float wl1 = Wl[(size_t)k * 128 + j + 64];
        float wr0 = Wr[(size_t)k * 128 + j];
        float wr1 = Wr[(size_t)k * 128 + j + 64];
        #pragma unroll
        for (int g = 0; g < GPT; g++) {
            const float4 xv = *(const float4*)&xs[k * NTP + (g0 + g * 4) * 4];
            aL0[g][0] += wl0 * xv.x; aL0[g][1] += wl0 * xv.y; aL0[g][2] += wl0 * xv.z; aL0[g][3] += wl0 * xv.w;
            aL1[g][0] += wl1 * xv.x; aL1[g][1] += wl1 * xv.y; aL1[g][2] += wl1 * xv.z; aL1[g][3] += wl1 * xv.w;
            aR0[g][0] += wr0 * xv.x; aR0[g][1] += wr0 * xv.y; aR0[g][2] += wr0 * xv.z; aR0[g][3] += wr0 * xv.w;
            aR1[g][0] += wr1 * xv.x; aR1[g][1] += wr1 * xv.y; aR1[g][2] += wr1 * xv.z; aR1[g][3] += wr1 * xv.w;
        }
    }

    float bl0 = bl[j], bl1 = bl[j + 64], br0 = br[j], br1 = br[j + 64];
    #pragma unroll
    for (int g = 0; g < GPT; g++) {
        int n0 = nb + (g0 + g * 4) * 4;
        #pragma unroll
        for (int c = 0; c < 4; c++) {
            size_t row = (size_t)(n0 + c) * 128;
            outl[row + j]      = __float2half(aL0[g][c] + bl0);
            outl[row + j + 64] = __float2half(aL1[g][c] + bl1);
            outr[row + j]      = aR0[g][c] + br0;
            outr[row + j + 64] = aR1[g][c] + br1;
        }
    }
}

// ===== dual linear FIN=128, FOUT=32 (global layer); xl->fp16, xr->fp32 =======
__launch_bounds__(256)
__global__ void k_ling(const float* __restrict__ x,
                       const float* __restrict__ Wl, const float* __restrict__ bl,
                       const float* __restrict__ Wr, const float* __restrict__ br,
                       __half* __restrict__ outl, float* __restrict__ outr) {
    constexpr int NT = 32, NTP = 36, FIN = 128;
    __shared__ float xs[FIN * NTP];
    int t = threadIdx.x, nb = blockIdx.x * NT;

    const float4* x4 = (const float4*)x;
    for (int idx = t; idx < NT * 32; idx += 256) {
        int node = idx >> 5, k4 = idx & 31;
        float4 v = x4[(size_t)(nb + node) * 32 + k4];
        xs[(k4 * 4 + 0) * NTP + node] = v.x;
        xs[(k4 * 4 + 1) * NTP + node] = v.y;
        xs[(k4 * 4 + 2) * NTP + node] = v.z;
        xs[(k4 * 4 + 3) * NTP + node] = v.w;
    }
    __syncthreads();

    int j = t & 31, g0 = t >> 5;  // 8 groups x 4 nodes
    float aL[4], aR[4];
    #pragma unroll
    for (int c = 0; c < 4; c++) { aL[c] = 0.f; aR[c] = 0.f; }

    #pragma unroll 4
    for (int k = 0; k < FIN; k++) {
        float wl = Wl[(size_t)k * 32 + j];
        float wr = Wr[(size_t)k * 32 + j];
        const float4 xv = *(const float4*)&xs[k * NTP + g0 * 4];
        aL[0] += wl * xv.x; aL[1] += wl * xv.y; aL[2] += wl * xv.z; aL[3] += wl * xv.w;
        aR[0] += wr * xv.x; aR[1] += wr * xv.y; aR[2] += wr * xv.z; aR[3] += wr * xv.w;
    }

    float blj = bl[j], brj = br[j];
    #pragma unroll
    for (int c = 0; c < 4; c++) {
        size_t row = (size_t)(nb + g0 * 4 + c) * 32;
        outl[row + j] = __float2half(aL[c] + blj);
        outr[row + j] = aR[c] + brj;
    }
}

// ===== fused GAT H=4 (F=128): wave/dst, 16 lanes/row (8 ch each), 4 edges/instr
__launch_bounds__(256)
__global__ void k_gat4h(const __half* __restrict__ xl, const float* __restrict__ xr,
                        const float* __restrict__ att,
                        const int* __restrict__ offs, const int* __restrict__ csr,
                        const float* __restrict__ bias, float* __restrict__ out,
                        int N) {
    int wave = threadIdx.x >> 6, lane = threadIdx.x & 63;
    int d = blockIdx.x * 4 + wave;
    if (d >= N) return;
    int grp = lane >> 4, sub = lane & 15;     // 4 edge-groups x 16 lanes
    int i0 = offs[d], i1 = offs[d + 1];

    float xrd[8], av[8], acc[8];
    {
        const float4* p4 = (const float4*)(xr + (size_t)d * 128 + sub * 8);
        float4 a = p4[0], b = p4[1];
        xrd[0]=a.x; xrd[1]=a.y; xrd[2]=a.z; xrd[3]=a.w;
        xrd[4]=b.x; xrd[5]=b.y; xrd[6]=b.z; xrd[7]=b.w;
        const float4* t4 = (const float4*)(att + sub * 8);
        float4 c = t4[0], e = t4[1];
        av[0]=c.x; av[1]=c.y; av[2]=c.z; av[3]=c.w;
        av[4]=e.x; av[5]=e.y; av[6]=e.z; av[7]=e.w;
    }
    #pragma unroll
    for (int c = 0; c < 8; c++) acc[c] = 0.f;
    float sm = 0.f;

    auto proc = [&](int s) {
        float4 raw = *(const float4*)(xl + (size_t)s * 128 + sub * 8);
        const __half2* h = (const __half2*)&raw;
        float v[8];
        float2 f;
        f = __half22float2(h[0]); v[0] = f.x; v[1] = f.y;
        f = __half22float2(h[1]); v[2] = f.x; v[3] = f.y;
        f = __half22float2(h[2]); v[4] = f.x; v[5] = f.y;
        f = __half22float2(h[3]); v[6] = f.x; v[7] = f.y;
        float p = 0.f;
        #pragma unroll
        for (int c = 0; c < 8; c++) {
            float u = v[c] + xrd[c];
            u = (u > 0.f) ? u : NEG_SLOPE * u;
            p += u * av[c];
        }
        p += __shfl_xor(p, 1);
        p += __shfl_xor(p, 2);
        p += __shfl_xor(p, 4);
        p += __shfl_xor(p, 8);
        float w = __expf(fminf(p, 80.f));
        sm += w;
        #pragma unroll
        for (int c = 0; c < 8; c++) acc[c] += w * v[c];
    };

    int i = i0 + grp;
    for (; i + 4 < i1; i += 8) {
        int s0 = csr[i], s1 = csr[i + 4];
        proc(s0); proc(s1);
    }
    for (; i < i1; i += 4) proc(csr[i]);

    // merge 4 edge-groups
    sm += __shfl_xor(sm, 16); sm += __shfl_xor(sm, 32);
    #pragma unroll
    for (int c = 0; c < 8; c++) {
        acc[c] += __shfl_xor(acc[c], 16);
        acc[c] += __shfl_xor(acc[c], 32);
    }
    if (grp == 0) {
        float inv = 1.f / (sm + 1e-16f);
        const float4* b4 = (const float4*)(bias + sub * 8);
        float4 b0 = b4[0], b1 = b4[1];
        float4 o0, o1;
        o0.x = fmaxf(acc[0] * inv + b0.x, 0.f);
        o0.y = fmaxf(acc[1] * inv + b0.y, 0.f);
        o0.z = fmaxf(acc[2] * inv + b0.z, 0.f);
        o0.w = fmaxf(acc[3] * inv + b0.w, 0.f);
        o1.x = fmaxf(acc[4] * inv + b1.x, 0.f);
        o1.y = fmaxf(acc[5] * inv + b1.y, 0.f);
        o1.z = fmaxf(acc[6] * inv + b1.z, 0.f);
        o1.w = fmaxf(acc[7] * inv + b1.w, 0.f);
        float4* op = (float4*)(out + (size_t)d * 128 + sub * 8);
        op[0] = o0; op[1] = o1;
    }
}

// ===== fused GAT H=1 (F=32): wave/dst, 8 lanes/row (4 ch each), 8 edges/instr
__launch_bounds__(256)
__global__ void k_gatgh(const __half* __restrict__ xl, const float* __restrict__ xr,
                        const float* __restrict__ att,
                        const int* __restrict__ offs, const int* __restrict__ csr,
                        const float* __restrict__ bias, float* __restrict__ out,
                        int N) {
    int wave = threadIdx.x >> 6, lane = threadIdx.x & 63;
    int d = blockIdx.x * 4 + wave;
    if (d >= N) return;
    int grp = lane >> 3, sub = lane & 7;      // 8 edge-groups x 8 lanes
    int i0 = offs[d], i1 = offs[d + 1];

    float xrd[4], av[4], acc[4];
    {
        float4 a = *(const float4*)(xr + (size_t)d * 32 + sub * 4);
        xrd[0]=a.x; xrd[1]=a.y; xrd[2]=a.z; xrd[3]=a.w;
        float4 c = *(const float4*)(att + sub * 4);
        av[0]=c.x; av[1]=c.y; av[2]=c.z; av[3]=c.w;
    }
    #pragma unroll
    for (int c = 0; c < 4; c++) acc[c] = 0.f;
    float sm = 0.f;

    auto proc = [&](int s) {
        float2 raw = *(const float2*)(xl + (size_t)s * 32 + sub * 4);
        const __half2* h = (const __half2*)&raw;
        float v[4];
        float2 f;
        f = __half22float2(h[0]); v[0] = f.x; v[1] = f.y;
        f = __half22float2(h[1]); v[2] = f.x; v[3] = f.y;
        float p = 0.f;
        #pragma unroll
        for (int c = 0; c < 4; c++) {
            float u = v[c] + xrd[c];
            u = (u > 0.f) ? u : NEG_SLOPE * u;
            p += u * av[c];
        }
        p += __shfl_xor(p, 1);
        p += __shfl_xor(p, 2);
        p += __shfl_xor(p, 4);
        float w = __expf(fminf(p, 80.f));
        sm += w;
        #pragma unroll
        for (int c = 0; c < 4; c++) acc[c] += w * v[c];
    };

    int i = i0 + grp;
    for (; i + 8 < i1; i += 16) {
        int s0 = csr[i], s1 = csr[i + 8];
        proc(s0); proc(s1);
    }
    for (; i < i1; i += 8) proc(csr[i]);

    // merge 8 edge-groups
    sm += __shfl_xor(sm, 8); sm += __shfl_xor(sm, 16); sm += __shfl_xor(sm, 32);
    #pragma unroll
    for (int c = 0; c < 4; c++) {
        acc[c] += __shfl_xor(acc[c], 8);
        acc[c] += __shfl_xor(acc[c], 16);
        acc[c] += __shfl_xor(acc[c], 32);
    }
    if (grp == 0) {
        float inv = 1.f / (sm + 1e-16f);
        float4 b = *(const float4*)(bias + sub * 4);
        float4 o;
        o.x = fmaxf(acc[0] * inv + b.x, 0.f);
        o.y = fmaxf(acc[1] * inv + b.y, 0.f);
        o.z = fmaxf(acc[2] * inv + b.z, 0.f);
        o.w = fmaxf(acc[3] * inv + b.w, 0.f);
        *(float4*)(out + (size_t)d * 32 + sub * 4) = o;
    }
}

// ================= tail =================
__global__ void k_tail(const float* __restrict__ gf, const int* __restrict__ focal,
                       const float* __restrict__ clf, const float* __restrict__ clW,
                       const float* __restrict__ clb, const float* __restrict__ fcW,
                       const float* __restrict__ fcb, void* __restrict__ out,
                       const int* __restrict__ flag) {
    int b = blockIdx.x;
    int t = threadIdx.x;
    __shared__ float comb[64];
    __shared__ float ssum[2];
    if (t < 2) {
        float s = 0.f;
        for (int l = 0; l < 50; l++) s += clf[(size_t)b * 100 + l * 2 + t];
        ssum[t] = s / 50.f;
    }
    if (t < 32) comb[t] = gf[(size_t)focal[b] * 32 + t];
    __syncthreads();
    if (t < 32) comb[32 + t] = ssum[0] * clW[t] + ssum[1] * clW[32 + t] + clb[t];
    __syncthreads();
    if (t < 60) {
        float acc = fcb[t];
        #pragma unroll 16
        for (int k = 0; k < 64; k++) acc += comb[k] * fcW[k * 60 + t];
        if (flag[0]) ((float*)out)[b * 60 + t] = acc;
        else ((bf16*)out)[b * 60 + t] = __float2bfloat16(acc);
    }
}

extern "C" void kernel_launch(void* const* d_in, const int* in_sizes, int n_in,
                              void* d_out, int out_size, void* d_ws, size_t ws_size,
                              hipStream_t stream) {
    const int* edge  = (const int*)d_in[1];
    const int* focal = (const int*)d_in[5];

    const int N = in_sizes[0] / 100;   // 20000
    const int E = in_sizes[1] / 2;     // 320000
    const int B = in_sizes[5];         // 64
    const int EA = E + N;
    const int* srcArr = edge;
    const int* dstArr = edge + E;

    // ---- conversion table: weights + centerlines -> fp32 in ws (x stays raw)
    const int idxs[NSEG] = {7,8,9,10,11,12,13,14,15,16,17,18,19,20,
                            35,36,37,38,39,40,41,42,43,44, 6};
    float* base = (float*)d_ws;
    int* flag = (int*)base;            // base[0..15] reserved
    float* wf = base + 16;
    Tab tab;
    int off[NSEG];
    int o = 0;
    for (int i = 0; i < NSEG; i++) {
        tab.s[i].src = d_in[idxs[i]];
        tab.s[i].n   = in_sizes[idxs[i]];
        tab.s[i].off = o;
        off[i] = o;
        o += in_sizes[idxs[i]];
    }
    const float* aeW  = wf + off[0],  *aeb  = wf + off[1];
    const float* a1Wl = wf + off[2],  *a1bl = wf + off[3];
    const float* a1Wr = wf + off[4],  *a1br = wf + off[5];
    const float* a1att= wf + off[6],  *a1b  = wf + off[7];
    const float* a2Wl = wf + off[8],  *a2bl = wf + off[9];
    const float* a2Wr = wf + off[10], *a2br = wf + off[11];
    const float* a2att= wf + off[12], *a2b  = wf + off[13];
    const float* clW  = wf + off[14], *clb  = wf + off[15];
    const float* gWl  = wf + off[16], *gbl  = wf + off[17];
    const float* gWr  = wf + off[18], *gbr  = wf + off[19];
    const float* gatt = wf + off[20], *gb   = wf + off[21];
    const float* fcW  = wf + off[22], *fcb  = wf + off[23];
    const float* clf  = wf + off[24];

    // ---- remaining workspace (keep 16B alignment) ----
    float* p = wf + o + ((4 - (o & 3)) & 3);
    size_t N128 = (size_t)N * 128;
    float* ax  = p;                 p += (size_t)N * 32;    // embed out (fp32)
    __half* hxl = (__half*)p;       p += (size_t)N * 64;    // xl fp16 [N,128]
    float* fB  = p;                 p += N128;              // xr fp32 (global: xrg+gf)
    float* fC  = p;                 p += N128;              // h / agent_features fp32
    int* deg    = (int*)p;
    int* cursor = deg + N;
    int* offs   = cursor + N;       // N+1
    int* csr    = offs + N + 1;     // EA (src node ids)
    int* bsum   = csr + EA;         // 64
    int* bpref  = bsum + 64;        // 64

    const int T = 256;
    const int NB = (N + 1023) / 1024;
    // ---- detect + zero deg/cursor ----
    k_detect_zero<<<64, 256, 0, stream>>>((const unsigned short*)d_in[0], flag, deg, 2 * N);
    // ---- convert weights + count degrees ----
    k_convert<<<256, 256, 0, stream>>>(tab, wf, flag, dstArr, E, N, deg);
    // ---- parallel scan ----
    k_scan1<<<NB, 1024, 0, stream>>>(deg, offs, bsum, N);
    k_scan2<<<1, 64, 0, stream>>>(bsum, bpref, offs, N, NB);
    k_addpref<<<NB, 1024, 0, stream>>>(offs, bpref, N);
    k_fill<<<(EA + T - 1) / T, T, 0, stream>>>(srcArr, dstArr, E, N, offs, cursor, csr);

    // ---- agent embedding ----
    k_embed<<<N / 32, 256, 0, stream>>>(d_in[0], aeW, aeb, ax, flag);

    // ---- conv1 ----
    k_lin2w<32, 32><<<N / 32, 256, 0, stream>>>(ax, a1Wl, a1bl, a1Wr, a1br, hxl, fB);
    k_gat4h<<<(N + 3) / 4, 256, 0, stream>>>(hxl, fB, a1att, offs, csr, a1b, fC, N);

    // ---- conv2 ----
    k_lin2w<128, 32><<<N / 32, 256, 0, stream>>>(fC, a2Wl, a2bl, a2Wr, a2br, hxl, fB);
    k_gat4h<<<(N + 3) / 4, 256, 0, stream>>>(hxl, fB, a2att, offs, csr, a2b, fC, N);

    // ---- global graph (heads=1) ----
    float* xrg = fB;
    float* gf  = fB + (size_t)N * 32;
    k_ling<<<N / 32, 256, 0, stream>>>(fC, gWl, gbl, gWr, gbr, hxl, xrg);
    k_gatgh<<<(N + 3) / 4, 256, 0, stream>>>(hxl, xrg, gatt, offs, csr, gb, gf, N);

    // ---- tail ----
    k_tail<<<B, 64, 0, stream>>>(gf, focal, clf, clW, clb, fcW, fcb, d_out, flag);
}